// Round 4
// baseline (807.386 us; speedup 1.0000x reference)
//
#include <hip/hip_runtime.h>

#define NN 50000
#define NE 800000
#define DIN 256
#define NH 3
#define HC 64
#define DD 192
#define DF 64
#define NB 196   // (NN + 255) / 256

typedef __attribute__((ext_vector_type(8))) short s8bf;   // 8 bf16 bit-patterns
typedef __attribute__((ext_vector_type(4))) float f32x4;

// ---- fp32 -> bf16 hi/lo split helpers ----
__device__ __forceinline__ unsigned short f2bf(float f) {
    unsigned u = __float_as_uint(f);
    unsigned r = u + 0x7fffu + ((u >> 16) & 1u);   // round-to-nearest-even
    return (unsigned short)(r >> 16);
}
__device__ __forceinline__ float bf2f(unsigned short h) {
    return __uint_as_float(((unsigned)h) << 16);
}
__device__ __forceinline__ void split2(float f, unsigned short& h, unsigned short& l) {
    h = f2bf(f);
    l = f2bf(f - bf2f(h));
}

// ---- split X [n*K] fp32 -> Xh, Xl bf16 (4 elems/thread) ----
__global__ __launch_bounds__(256)
void split_x(const float* __restrict__ X, unsigned short* __restrict__ Xh,
             unsigned short* __restrict__ Xl, int total) {
    int i = (blockIdx.x * 256 + threadIdx.x) * 4;
    if (i >= total) return;
    float4 v = *(const float4*)(X + i);
    ushort4 h, l;
    split2(v.x, h.x, l.x); split2(v.y, h.y, l.y);
    split2(v.z, h.z, l.z); split2(v.w, h.w, l.w);
    *(ushort4*)(Xh + i) = h;
    *(ushort4*)(Xl + i) = l;
}

// ---- split + transpose W [K,D] fp32 -> WhT, WlT [D,K] bf16 ----
template<int K, int D>
__global__ __launch_bounds__(256)
void wsplit_T(const float* __restrict__ W, unsigned short* __restrict__ WhT,
              unsigned short* __restrict__ WlT) {
    int idx = blockIdx.x * 256 + threadIdx.x;
    if (idx >= K * D) return;
    int k = idx / D, d = idx - k * D;
    unsigned short h, l;
    split2(W[idx], h, l);
    WhT[d * K + k] = h;
    WlT[d * K + k] = l;
}

// ---- split-bf16 MFMA GEMM: Y[n,DOUT] = (Ah+Al) @ (Bh+Bl)^T^T (+bias) ----
// 256 thr = 4 waves; wave -> 16 rows x DOUT cols; frags direct from global.
template<int K, int DOUT, bool BIAS>
__global__ __launch_bounds__(256)
void mfma_gemm(const unsigned short* __restrict__ Ah, const unsigned short* __restrict__ Al,
               const unsigned short* __restrict__ BhT, const unsigned short* __restrict__ BlT,
               const float* __restrict__ bias, float* __restrict__ Y, int n) {
    constexpr int NT = DOUT / 16;
    const int wave = threadIdx.x >> 6, lane = threadIdx.x & 63;
    const int r = lane & 15, kg = lane >> 4;
    const int row0 = blockIdx.x * 64 + wave * 16;
    const int arow = min(row0 + r, n - 1);

    f32x4 acc[NT] = {};
    const unsigned short* pa_h = Ah + (size_t)arow * K + kg * 8;
    const unsigned short* pa_l = Al + (size_t)arow * K + kg * 8;
    const size_t bbase = (size_t)r * K + kg * 8;

    for (int k0 = 0; k0 < K; k0 += 32) {
        s8bf ah = *(const s8bf*)(pa_h + k0);
        s8bf al = *(const s8bf*)(pa_l + k0);
#pragma unroll
        for (int t = 0; t < NT; ++t) {
            size_t bo = bbase + (size_t)t * 16 * K + k0;
            s8bf bh = *(const s8bf*)(BhT + bo);
            s8bf bl = *(const s8bf*)(BlT + bo);
            acc[t] = __builtin_amdgcn_mfma_f32_16x16x32_bf16(ah, bh, acc[t], 0, 0, 0);
            acc[t] = __builtin_amdgcn_mfma_f32_16x16x32_bf16(ah, bl, acc[t], 0, 0, 0);
            acc[t] = __builtin_amdgcn_mfma_f32_16x16x32_bf16(al, bh, acc[t], 0, 0, 0);
        }
    }

    // D layout: col = lane&15, row = (lane>>4)*4 + reg   [m89 verified]
#pragma unroll
    for (int t = 0; t < NT; ++t) {
        int col = t * 16 + r;
        float b = BIAS ? bias[col] : 0.f;
#pragma unroll
        for (int rr = 0; rr < 4; ++rr) {
            int row = row0 + kg * 4 + rr;
            if (row < n) Y[(size_t)row * DOUT + col] = acc[t][rr] + b;
        }
    }
}

// ---- per-node attention dots ----
__global__ __launch_bounds__(192)
void attn_dots(const float* __restrict__ xf,
               const float* __restrict__ att_s, const float* __restrict__ att_d,
               float* __restrict__ as_, float* __restrict__ ad_) {
    int nidx = blockIdx.x;
    int h = threadIdx.x >> 6;
    int lane = threadIdx.x & 63;
    float v = xf[(size_t)nidx * DD + h * HC + lane];
    float s = v * att_s[h * HC + lane];
    float d = v * att_d[h * HC + lane];
#pragma unroll
    for (int off = 32; off; off >>= 1) {
        s += __shfl_down(s, off);
        d += __shfl_down(d, off);
    }
    if (lane == 0) {
        as_[nidx * NH + h] = s;
        ad_[nidx * NH + h] = d;
    }
}

// ============ CSR build ============
__global__ void hist_kernel(const int* __restrict__ dst, int* __restrict__ deg, int ne) {
    int e = blockIdx.x * blockDim.x + threadIdx.x;
    if (e < ne) atomicAdd(&deg[dst[e]], 1);
}

__global__ __launch_bounds__(256)
void blocksum_kernel(const int* __restrict__ deg, int* __restrict__ bsum) {
    int i = blockIdx.x * 256 + threadIdx.x;
    int v = (i < NN) ? deg[i] : 0;
#pragma unroll
    for (int off = 32; off; off >>= 1) v += __shfl_down(v, off);
    __shared__ int ws[4];
    if ((threadIdx.x & 63) == 0) ws[threadIdx.x >> 6] = v;
    __syncthreads();
    if (threadIdx.x == 0) bsum[blockIdx.x] = ws[0] + ws[1] + ws[2] + ws[3];
}

__global__ __launch_bounds__(256)
void scan_bsums(const int* __restrict__ bsum, int* __restrict__ boff,
                int* __restrict__ rowptr) {
    __shared__ int s[256];
    int t = threadIdx.x;
    int v = (t < NB) ? bsum[t] : 0;
    s[t] = v;
    __syncthreads();
    for (int off = 1; off < 256; off <<= 1) {
        int u = (t >= off) ? s[t - off] : 0;
        __syncthreads();
        s[t] += u;
        __syncthreads();
    }
    if (t < NB) boff[t] = s[t] - v;
    if (t == 255) rowptr[NN] = s[255];
}

__global__ __launch_bounds__(256)
void expand_kernel(const int* __restrict__ deg, const int* __restrict__ boff,
                   int* __restrict__ rowptr, int* __restrict__ cursor) {
    __shared__ int s[256];
    int t = threadIdx.x;
    int i = blockIdx.x * 256 + t;
    int v = (i < NN) ? deg[i] : 0;
    s[t] = v;
    __syncthreads();
    for (int off = 1; off < 256; off <<= 1) {
        int u = (t >= off) ? s[t - off] : 0;
        __syncthreads();
        s[t] += u;
        __syncthreads();
    }
    if (i < NN) {
        int excl = s[t] - v + boff[blockIdx.x];
        rowptr[i] = excl;
        cursor[i] = excl;
    }
}

__global__ void scatter_kernel(const int* __restrict__ src, const int* __restrict__ dst,
                               int* __restrict__ cursor, int* __restrict__ csr_src, int ne) {
    int e = blockIdx.x * blockDim.x + threadIdx.x;
    if (e >= ne) return;
    int d = dst[e];
    int pos = atomicAdd(&cursor[d], 1);
    csr_src[pos] = src[e];
}

// ============ fused GAT gather: one wave per (node, head) ============
__global__ __launch_bounds__(256)
void gat_gather(const float* __restrict__ xf,
                const float* __restrict__ as_, const float* __restrict__ ad_,
                const int* __restrict__ rowptr, const int* __restrict__ csr_src,
                float* __restrict__ outp) {
    int wid = blockIdx.x * 4 + (threadIdx.x >> 6);   // < NN*NH exactly
    int d = wid / NH, h = wid - d * NH;
    int lane = threadIdx.x & 63;
    int beg = rowptr[d], end = rowptr[d + 1];
    float adh = ad_[d * NH + h];

    // pass 1: max over incoming edges (lanes parallel over edges)
    float m = -1e30f;
    for (int i = beg + lane; i < end; i += 64) {
        float e = as_[csr_src[i] * NH + h] + adh;
        e = e > 0.f ? e : 0.2f * e;
        m = fmaxf(m, e);
    }
#pragma unroll
    for (int off = 1; off < 64; off <<= 1) m = fmaxf(m, __shfl_xor(m, off));

    // pass 2: serial edge walk, 2-way unrolled; lane owns channel h*64+lane
    const float* xb = xf + h * HC + lane;
    float a = 0.f, den = 0.f;
    int i = beg;
    for (; i + 1 < end; i += 2) {
        int s0 = __builtin_amdgcn_readfirstlane(csr_src[i]);
        int s1 = __builtin_amdgcn_readfirstlane(csr_src[i + 1]);
        float e0 = as_[s0 * NH + h] + adh; e0 = e0 > 0.f ? e0 : 0.2f * e0;
        float e1 = as_[s1 * NH + h] + adh; e1 = e1 > 0.f ? e1 : 0.2f * e1;
        float w0 = __expf(e0 - m), w1 = __expf(e1 - m);
        den += w0 + w1;
        a = fmaf(xb[(size_t)s0 * DD], w0, a);
        a = fmaf(xb[(size_t)s1 * DD], w1, a);
    }
    if (i < end) {
        int s0 = __builtin_amdgcn_readfirstlane(csr_src[i]);
        float e0 = as_[s0 * NH + h] + adh; e0 = e0 > 0.f ? e0 : 0.2f * e0;
        float w0 = __expf(e0 - m);
        den += w0;
        a = fmaf(xb[(size_t)s0 * DD], w0, a);
    }
    outp[(size_t)d * DD + h * HC + lane] = a / (den + 1e-16f);
}

// ---- BN pass 1: per-feature sum / sumsq of relu(h + bias) ----
__global__ __launch_bounds__(192)
void bn_stats(const float* __restrict__ hbuf, const float* __restrict__ bias,
              float* __restrict__ s1, float* __restrict__ s2, int n) {
    int j = threadIdx.x;
    float b = bias[j];
    int r0 = blockIdx.x * 128;
    int r1 = min(r0 + 128, n);
    float a = 0.f, q = 0.f;
    for (int r = r0; r < r1; ++r) {
        float v = hbuf[(size_t)r * DD + j] + b;
        v = fmaxf(v, 0.f);
        a += v; q += v * v;
    }
    atomicAdd(&s1[j], a);
    atomicAdd(&s2[j], q);
}

__global__ void bn_finalize(const float* __restrict__ s1, const float* __restrict__ s2,
                            const float* __restrict__ g, const float* __restrict__ beta,
                            float* __restrict__ scale, float* __restrict__ shift, float invn) {
    int j = threadIdx.x;
    float mu = s1[j] * invn;
    float var = s2[j] * invn - mu * mu;
    float sc = g[j] * rsqrtf(var + 1e-5f);
    scale[j] = sc;
    shift[j] = beta[j] - mu * sc;
}

// ---- BN apply #1: writes fp32 H1 + bf16 hi/lo (for next GEMM) ----
__global__ __launch_bounds__(256)
void bn_apply_split(const float* __restrict__ in, const float* __restrict__ bias,
                    const float* __restrict__ scale, const float* __restrict__ shift,
                    float* __restrict__ outf, unsigned short* __restrict__ oh,
                    unsigned short* __restrict__ ol, int total) {
    int i = (blockIdx.x * 256 + threadIdx.x) * 4;
    if (i >= total) return;
    int j = i % DD;
    float4 v = *(const float4*)(in + i);
    float4 b = *(const float4*)(bias + j);
    float4 sc = *(const float4*)(scale + j);
    float4 sh = *(const float4*)(shift + j);
    float4 y;
    y.x = fmaxf(v.x + b.x, 0.f) * sc.x + sh.x;
    y.y = fmaxf(v.y + b.y, 0.f) * sc.y + sh.y;
    y.z = fmaxf(v.z + b.z, 0.f) * sc.z + sh.z;
    y.w = fmaxf(v.w + b.w, 0.f) * sc.w + sh.w;
    *(float4*)(outf + i) = y;
    ushort4 h, l;
    split2(y.x, h.x, l.x); split2(y.y, h.y, l.y);
    split2(y.z, h.z, l.z); split2(y.w, h.w, l.w);
    *(ushort4*)(oh + i) = h;
    *(ushort4*)(ol + i) = l;
}

// ---- BN apply #2: y = bn(relu(in+bias)); s = y + H1; writes bf16 hi/lo of s ----
__global__ __launch_bounds__(256)
void bn_apply_sum_split(const float* __restrict__ in, const float* __restrict__ bias,
                        const float* __restrict__ scale, const float* __restrict__ shift,
                        const float* __restrict__ h1, unsigned short* __restrict__ oh,
                        unsigned short* __restrict__ ol, int total) {
    int i = (blockIdx.x * 256 + threadIdx.x) * 4;
    if (i >= total) return;
    int j = i % DD;
    float4 v = *(const float4*)(in + i);
    float4 b = *(const float4*)(bias + j);
    float4 sc = *(const float4*)(scale + j);
    float4 sh = *(const float4*)(shift + j);
    float4 u = *(const float4*)(h1 + i);
    float4 y;
    y.x = fmaxf(v.x + b.x, 0.f) * sc.x + sh.x + u.x;
    y.y = fmaxf(v.y + b.y, 0.f) * sc.y + sh.y + u.y;
    y.z = fmaxf(v.z + b.z, 0.f) * sc.z + sh.z + u.z;
    y.w = fmaxf(v.w + b.w, 0.f) * sc.w + sh.w + u.w;
    ushort4 h, l;
    split2(y.x, h.x, l.x); split2(y.y, h.y, l.y);
    split2(y.z, h.z, l.z); split2(y.w, h.w, l.w);
    *(ushort4*)(oh + i) = h;
    *(ushort4*)(ol + i) = l;
}

extern "C" void kernel_launch(void* const* d_in, const int* in_sizes, int n_in,
                              void* d_out, int out_size, void* d_ws, size_t ws_size,
                              hipStream_t stream) {
    const float* x   = (const float*)d_in[0];
    const float* W1  = (const float*)d_in[1];
    const float* as1 = (const float*)d_in[2];
    const float* ad1 = (const float*)d_in[3];
    const float* b1  = (const float*)d_in[4];
    const float* g1  = (const float*)d_in[5];
    const float* be1 = (const float*)d_in[6];
    const float* W2  = (const float*)d_in[7];
    const float* as2 = (const float*)d_in[8];
    const float* ad2 = (const float*)d_in[9];
    const float* b2  = (const float*)d_in[10];
    const float* g2  = (const float*)d_in[11];
    const float* be2 = (const float*)d_in[12];
    const float* Wf  = (const float*)d_in[13];
    const float* bf  = (const float*)d_in[14];
    const int*   ei  = (const int*)d_in[15];
    const int* src = ei;
    const int* dst = ei + NE;
    float* out = (float*)d_out;

    float* ws = (float*)d_ws;
    float* A   = ws;                          // [N,192] layer features (fp32)
    float* H1  = A   + (size_t)NN * DD;       // [N,192] h1 post-BN (fp32)
    float* CB  = H1  + (size_t)NN * DD;       // [N,192] aggregate
    float* AS  = CB  + (size_t)NN * DD;       // [N,3]
    float* AD  = AS  + (size_t)NN * NH;       // [N,3]
    float* S1  = AD  + (size_t)NN * NH;       // [192]
    float* S2  = S1 + DD;
    float* SC  = S2 + DD;
    float* SH  = SC + DD;
    int* DEG    = (int*)(SH + DD);            // [N]
    int* ROWPTR = DEG + NN;                   // [N+1]
    int* CURSOR = ROWPTR + NN + 1;            // [N]
    int* BSUM   = CURSOR + NN;                // [NB]
    int* BOFF   = BSUM + NB;                  // [NB]
    int* CSRS   = BOFF + NB;                  // [E]
    // bf16 region R: phases (Xh,Xl)->(Hh,Hl)->(Sh,Sl); then weight splits
    unsigned short* R    = (unsigned short*)(CSRS + NE);
    unsigned short* Xh   = R;                          // [N,256]
    unsigned short* Xl   = R + (size_t)NN * DIN;
    unsigned short* Hh   = R;                          // [N,192]
    unsigned short* Hl   = R + (size_t)NN * DD;
    unsigned short* Sh   = R;                          // [N,192]
    unsigned short* Sl   = R + (size_t)NN * DD;
    unsigned short* W1hT = R + 2 * (size_t)NN * DIN;   // [192,256]
    unsigned short* W1lT = W1hT + DIN * DD;
    unsigned short* W2hT = W1lT + DIN * DD;            // [192,192]
    unsigned short* W2lT = W2hT + DD * DD;
    unsigned short* WfhT = W2lT + DD * DD;             // [64,192]
    unsigned short* WflT = WfhT + DD * DF;

    const int edge_grid = (NE + 255) / 256;
    const int gemm_grid = (NN + 63) / 64;
    const int gat_grid  = (NN * NH) / 4;      // 37500, exact
    const int bns_grid  = (NN + 127) / 128;
    const int bna_grid  = (NN * DD / 4 + 255) / 256;

    // ---- CSR build (once) ----
    hipMemsetAsync(DEG, 0, (size_t)NN * 4, stream);
    hist_kernel<<<edge_grid, 256, 0, stream>>>(dst, DEG, NE);
    blocksum_kernel<<<NB, 256, 0, stream>>>(DEG, BSUM);
    scan_bsums<<<1, 256, 0, stream>>>(BSUM, BOFF, ROWPTR);
    expand_kernel<<<NB, 256, 0, stream>>>(DEG, BOFF, ROWPTR, CURSOR);
    scatter_kernel<<<edge_grid, 256, 0, stream>>>(src, dst, CURSOR, CSRS, NE);

    // ---- weight + input splits ----
    split_x<<<(NN * DIN / 4 + 255) / 256, 256, 0, stream>>>(x, Xh, Xl, NN * DIN);
    wsplit_T<DIN, DD><<<(DIN * DD + 255) / 256, 256, 0, stream>>>(W1, W1hT, W1lT);
    wsplit_T<DD, DD><<<(DD * DD + 255) / 256, 256, 0, stream>>>(W2, W2hT, W2lT);
    wsplit_T<DD, DF><<<(DD * DF + 255) / 256, 256, 0, stream>>>(Wf, WfhT, WflT);

    // ================= layer 1 =================
    mfma_gemm<DIN, DD, false><<<gemm_grid, 256, 0, stream>>>(Xh, Xl, W1hT, W1lT, nullptr, A, NN);
    attn_dots<<<NN, 192, 0, stream>>>(A, as1, ad1, AS, AD);
    gat_gather<<<gat_grid, 256, 0, stream>>>(A, AS, AD, ROWPTR, CSRS, CB);
    hipMemsetAsync(S1, 0, 2 * DD * 4, stream);
    bn_stats<<<bns_grid, 192, 0, stream>>>(CB, b1, S1, S2, NN);
    bn_finalize<<<1, DD, 0, stream>>>(S1, S2, g1, be1, SC, SH, 1.0f / NN);
    bn_apply_split<<<bna_grid, 256, 0, stream>>>(CB, b1, SC, SH, H1, Hh, Hl, NN * DD);

    // ================= layer 2 =================
    mfma_gemm<DD, DD, false><<<gemm_grid, 256, 0, stream>>>(Hh, Hl, W2hT, W2lT, nullptr, A, NN);
    attn_dots<<<NN, 192, 0, stream>>>(A, as2, ad2, AS, AD);
    gat_gather<<<gat_grid, 256, 0, stream>>>(A, AS, AD, ROWPTR, CSRS, CB);
    hipMemsetAsync(S1, 0, 2 * DD * 4, stream);
    bn_stats<<<bns_grid, 192, 0, stream>>>(CB, b2, S1, S2, NN);
    bn_finalize<<<1, DD, 0, stream>>>(S1, S2, g2, be2, SC, SH, 1.0f / NN);
    bn_apply_sum_split<<<bna_grid, 256, 0, stream>>>(CB, b2, SC, SH, H1, Sh, Sl, NN * DD);

    // ================= final: out = (h1 + h2) @ Wf + bf =================
    mfma_gemm<DD, DF, true><<<gemm_grid, 256, 0, stream>>>(Sh, Sl, WfhT, WflT, bf, out, NN);
}

// Round 5
// 595.693 us; speedup vs baseline: 1.3554x; 1.3554x over previous
//
#include <hip/hip_runtime.h>

#define NN 50000
#define NE 800000
#define DIN 256
#define NH 3
#define HC 64
#define DD 192
#define DF 64
#define NB 196   // (NN + 255) / 256

typedef __attribute__((ext_vector_type(8))) short s8bf;   // 8 bf16 bit-patterns
typedef __attribute__((ext_vector_type(4))) float f32x4;

// ---- fp32 -> bf16 helpers ----
__device__ __forceinline__ unsigned short f2bf(float f) {
    unsigned u = __float_as_uint(f);
    unsigned r = u + 0x7fffu + ((u >> 16) & 1u);   // round-to-nearest-even
    return (unsigned short)(r >> 16);
}
__device__ __forceinline__ float bf2f(unsigned short h) {
    return __uint_as_float(((unsigned)h) << 16);
}
__device__ __forceinline__ void split2(float f, unsigned short& h, unsigned short& l) {
    h = f2bf(f);
    l = f2bf(f - bf2f(h));
}

// ---- split X [n*K] fp32 -> Xh, Xl bf16 ----
__global__ __launch_bounds__(256)
void split_x(const float* __restrict__ X, unsigned short* __restrict__ Xh,
             unsigned short* __restrict__ Xl, int total) {
    int i = (blockIdx.x * 256 + threadIdx.x) * 4;
    if (i >= total) return;
    float4 v = *(const float4*)(X + i);
    ushort4 h, l;
    split2(v.x, h.x, l.x); split2(v.y, h.y, l.y);
    split2(v.z, h.z, l.z); split2(v.w, h.w, l.w);
    *(ushort4*)(Xh + i) = h;
    *(ushort4*)(Xl + i) = l;
}

// ---- split + transpose W [K,D] fp32 -> WhT, WlT [D,K] bf16 ----
template<int K, int D>
__global__ __launch_bounds__(256)
void wsplit_T(const float* __restrict__ W, unsigned short* __restrict__ WhT,
              unsigned short* __restrict__ WlT) {
    int idx = blockIdx.x * 256 + threadIdx.x;
    if (idx >= K * D) return;
    int k = idx / D, d = idx - k * D;
    unsigned short h, l;
    split2(W[idx], h, l);
    WhT[d * K + k] = h;
    WlT[d * K + k] = l;
}

// ---- split-bf16 MFMA GEMM, A-fragment sources by MODE ----
// MODE 0: A = (Ah,Al) bf16 pair from global; output bf16 Yb
// MODE 1: A = bn1(relu(C1 + b1)) built on the fly; output bf16 Yb
// MODE 2: A = bn1(relu(C1+b1)) + bn2(relu(C2+b2)); output fp32 Yf + obias
template<int K, int DOUT, int MODE>
__global__ __launch_bounds__(256)
void mfma_gemm(const unsigned short* __restrict__ Ah, const unsigned short* __restrict__ Al,
               const float* __restrict__ C1, const float* __restrict__ b1,
               const float* __restrict__ sc1, const float* __restrict__ sh1,
               const float* __restrict__ C2, const float* __restrict__ b2,
               const float* __restrict__ sc2, const float* __restrict__ sh2,
               const unsigned short* __restrict__ BhT, const unsigned short* __restrict__ BlT,
               const float* __restrict__ obias, float* __restrict__ Yf,
               unsigned short* __restrict__ Yb, int n) {
    constexpr int NT = DOUT / 16;
    const int wave = threadIdx.x >> 6, lane = threadIdx.x & 63;
    const int r = lane & 15, kg = lane >> 4;
    const int row0 = blockIdx.x * 64 + wave * 16;
    const int arow = min(row0 + r, n - 1);
    const size_t bbase = (size_t)r * K + kg * 8;

    f32x4 acc[NT] = {};

    for (int k0 = 0; k0 < K; k0 += 32) {
        s8bf ah, al;
        if constexpr (MODE == 0) {
            ah = *(const s8bf*)(Ah + (size_t)arow * K + kg * 8 + k0);
            al = *(const s8bf*)(Al + (size_t)arow * K + kg * 8 + k0);
        } else {
            const int kb = kg * 8 + k0;
            const float* c1p = C1 + (size_t)arow * K + kb;
            float y[8];
#pragma unroll
            for (int j = 0; j < 8; ++j) {
                float v = fmaxf(c1p[j] + b1[kb + j], 0.f) * sc1[kb + j] + sh1[kb + j];
                if constexpr (MODE == 2) {
                    float u = fmaxf(C2[(size_t)arow * K + kb + j] + b2[kb + j], 0.f)
                              * sc2[kb + j] + sh2[kb + j];
                    v += u;
                }
                y[j] = v;
            }
#pragma unroll
            for (int j = 0; j < 8; ++j) {
                unsigned short hh, ll;
                split2(y[j], hh, ll);
                ah[j] = (short)hh; al[j] = (short)ll;
            }
        }
#pragma unroll
        for (int t = 0; t < NT; ++t) {
            size_t bo = bbase + (size_t)t * 16 * K + k0;
            s8bf bh = *(const s8bf*)(BhT + bo);
            s8bf bl = *(const s8bf*)(BlT + bo);
            acc[t] = __builtin_amdgcn_mfma_f32_16x16x32_bf16(ah, bh, acc[t], 0, 0, 0);
            acc[t] = __builtin_amdgcn_mfma_f32_16x16x32_bf16(ah, bl, acc[t], 0, 0, 0);
            acc[t] = __builtin_amdgcn_mfma_f32_16x16x32_bf16(al, bh, acc[t], 0, 0, 0);
        }
    }

    // C layout: col = lane&15, row = (lane>>4)*4 + reg
#pragma unroll
    for (int t = 0; t < NT; ++t) {
        int col = t * 16 + r;
        float b = (MODE == 2) ? obias[col] : 0.f;
#pragma unroll
        for (int rr = 0; rr < 4; ++rr) {
            int row = row0 + kg * 4 + rr;
            if (row < n) {
                if constexpr (MODE == 2)
                    Yf[(size_t)row * DOUT + col] = acc[t][rr] + b;
                else
                    Yb[(size_t)row * DOUT + col] = f2bf(acc[t][rr]);
            }
        }
    }
}

// ---- per-node attention dots (bf16 features) ----
__global__ __launch_bounds__(192)
void attn_dots(const unsigned short* __restrict__ xf,
               const float* __restrict__ att_s, const float* __restrict__ att_d,
               float* __restrict__ as_, float* __restrict__ ad_) {
    int nidx = blockIdx.x;
    int h = threadIdx.x >> 6;
    int lane = threadIdx.x & 63;
    float v = bf2f(xf[(size_t)nidx * DD + h * HC + lane]);
    float s = v * att_s[h * HC + lane];
    float d = v * att_d[h * HC + lane];
#pragma unroll
    for (int off = 32; off; off >>= 1) {
        s += __shfl_down(s, off);
        d += __shfl_down(d, off);
    }
    if (lane == 0) {
        as_[nidx * NH + h] = s;
        ad_[nidx * NH + h] = d;
    }
}

// ============ CSR build ============
__global__ void hist_kernel(const int* __restrict__ dst, int* __restrict__ deg, int ne) {
    int e = blockIdx.x * blockDim.x + threadIdx.x;
    if (e < ne) atomicAdd(&deg[dst[e]], 1);
}

__global__ __launch_bounds__(256)
void blocksum_kernel(const int* __restrict__ deg, int* __restrict__ bsum) {
    int i = blockIdx.x * 256 + threadIdx.x;
    int v = (i < NN) ? deg[i] : 0;
#pragma unroll
    for (int off = 32; off; off >>= 1) v += __shfl_down(v, off);
    __shared__ int ws[4];
    if ((threadIdx.x & 63) == 0) ws[threadIdx.x >> 6] = v;
    __syncthreads();
    if (threadIdx.x == 0) bsum[blockIdx.x] = ws[0] + ws[1] + ws[2] + ws[3];
}

__global__ __launch_bounds__(256)
void scan_bsums(const int* __restrict__ bsum, int* __restrict__ boff,
                int* __restrict__ rowptr) {
    __shared__ int s[256];
    int t = threadIdx.x;
    int v = (t < NB) ? bsum[t] : 0;
    s[t] = v;
    __syncthreads();
    for (int off = 1; off < 256; off <<= 1) {
        int u = (t >= off) ? s[t - off] : 0;
        __syncthreads();
        s[t] += u;
        __syncthreads();
    }
    if (t < NB) boff[t] = s[t] - v;
    if (t == 255) rowptr[NN] = s[255];
}

__global__ __launch_bounds__(256)
void expand_kernel(const int* __restrict__ deg, const int* __restrict__ boff,
                   int* __restrict__ rowptr, int* __restrict__ cursor) {
    __shared__ int s[256];
    int t = threadIdx.x;
    int i = blockIdx.x * 256 + t;
    int v = (i < NN) ? deg[i] : 0;
    s[t] = v;
    __syncthreads();
    for (int off = 1; off < 256; off <<= 1) {
        int u = (t >= off) ? s[t - off] : 0;
        __syncthreads();
        s[t] += u;
        __syncthreads();
    }
    if (i < NN) {
        int excl = s[t] - v + boff[blockIdx.x];
        rowptr[i] = excl;
        cursor[i] = excl;
    }
}

__global__ void scatter_kernel(const int* __restrict__ src, const int* __restrict__ dst,
                               int* __restrict__ cursor, int* __restrict__ csr_src, int ne) {
    int e = blockIdx.x * blockDim.x + threadIdx.x;
    if (e >= ne) return;
    int d = dst[e];
    int pos = atomicAdd(&cursor[d], 1);
    csr_src[pos] = src[e];
}

// ============ fused GAT gather: softmax (no-max) + aggregate ============
// one wave per dst node; lane owns channels {lane, lane+64, lane+128}; bf16 feats
__global__ __launch_bounds__(256)
void gat_gather(const unsigned short* __restrict__ xf,
                const float* __restrict__ as_, const float* __restrict__ ad_,
                const int* __restrict__ rowptr, const int* __restrict__ csr_src,
                float* __restrict__ outp) {
    int d = blockIdx.x * 4 + (threadIdx.x >> 6);
    if (d >= NN) return;
    int lane = threadIdx.x & 63;
    int beg = rowptr[d], end = rowptr[d + 1];
    float ad0 = ad_[d * NH + 0], ad1 = ad_[d * NH + 1], ad2 = ad_[d * NH + 2];

    float a0 = 0.f, a1 = 0.f, a2 = 0.f;
    float den0 = 0.f, den1 = 0.f, den2 = 0.f;
    int i = beg;
    for (; i + 1 < end; i += 2) {
        int s0 = __builtin_amdgcn_readfirstlane(csr_src[i]);
        int s1 = __builtin_amdgcn_readfirstlane(csr_src[i + 1]);
        float e00 = as_[s0 * NH + 0] + ad0, e01 = as_[s0 * NH + 1] + ad1, e02 = as_[s0 * NH + 2] + ad2;
        float e10 = as_[s1 * NH + 0] + ad0, e11 = as_[s1 * NH + 1] + ad1, e12 = as_[s1 * NH + 2] + ad2;
        e00 = e00 > 0.f ? e00 : 0.2f * e00;  e01 = e01 > 0.f ? e01 : 0.2f * e01;  e02 = e02 > 0.f ? e02 : 0.2f * e02;
        e10 = e10 > 0.f ? e10 : 0.2f * e10;  e11 = e11 > 0.f ? e11 : 0.2f * e11;  e12 = e12 > 0.f ? e12 : 0.2f * e12;
        float w00 = __expf(e00), w01 = __expf(e01), w02 = __expf(e02);
        float w10 = __expf(e10), w11 = __expf(e11), w12 = __expf(e12);
        const unsigned short* x0 = xf + (size_t)s0 * DD;
        const unsigned short* x1 = xf + (size_t)s1 * DD;
        float f00 = bf2f(x0[lane]), f01 = bf2f(x0[64 + lane]), f02 = bf2f(x0[128 + lane]);
        float f10 = bf2f(x1[lane]), f11 = bf2f(x1[64 + lane]), f12 = bf2f(x1[128 + lane]);
        den0 += w00 + w10; den1 += w01 + w11; den2 += w02 + w12;
        a0 = fmaf(f00, w00, a0); a0 = fmaf(f10, w10, a0);
        a1 = fmaf(f01, w01, a1); a1 = fmaf(f11, w11, a1);
        a2 = fmaf(f02, w02, a2); a2 = fmaf(f12, w12, a2);
    }
    if (i < end) {
        int s0 = __builtin_amdgcn_readfirstlane(csr_src[i]);
        float e00 = as_[s0 * NH + 0] + ad0, e01 = as_[s0 * NH + 1] + ad1, e02 = as_[s0 * NH + 2] + ad2;
        e00 = e00 > 0.f ? e00 : 0.2f * e00;  e01 = e01 > 0.f ? e01 : 0.2f * e01;  e02 = e02 > 0.f ? e02 : 0.2f * e02;
        float w00 = __expf(e00), w01 = __expf(e01), w02 = __expf(e02);
        const unsigned short* x0 = xf + (size_t)s0 * DD;
        den0 += w00; den1 += w01; den2 += w02;
        a0 = fmaf(bf2f(x0[lane]),       w00, a0);
        a1 = fmaf(bf2f(x0[64 + lane]),  w01, a1);
        a2 = fmaf(bf2f(x0[128 + lane]), w02, a2);
    }
    size_t o = (size_t)d * DD + lane;
    outp[o]       = a0 / (den0 + 1e-16f);
    outp[o + 64]  = a1 / (den1 + 1e-16f);
    outp[o + 128] = a2 / (den2 + 1e-16f);
}

// ---- BN pass 1: per-feature sum / sumsq of relu(h + bias) ----
__global__ __launch_bounds__(192)
void bn_stats(const float* __restrict__ hbuf, const float* __restrict__ bias,
              float* __restrict__ s1, float* __restrict__ s2, int n) {
    int j = threadIdx.x;
    float b = bias[j];
    int r0 = blockIdx.x * 128;
    int r1 = min(r0 + 128, n);
    float a = 0.f, q = 0.f;
    for (int r = r0; r < r1; ++r) {
        float v = hbuf[(size_t)r * DD + j] + b;
        v = fmaxf(v, 0.f);
        a += v; q += v * v;
    }
    atomicAdd(&s1[j], a);
    atomicAdd(&s2[j], q);
}

__global__ void bn_finalize(const float* __restrict__ s1, const float* __restrict__ s2,
                            const float* __restrict__ g, const float* __restrict__ beta,
                            float* __restrict__ scale, float* __restrict__ shift, float invn) {
    int j = threadIdx.x;
    float mu = s1[j] * invn;
    float var = s2[j] * invn - mu * mu;
    float sc = g[j] * rsqrtf(var + 1e-5f);
    scale[j] = sc;
    shift[j] = beta[j] - mu * sc;
}

extern "C" void kernel_launch(void* const* d_in, const int* in_sizes, int n_in,
                              void* d_out, int out_size, void* d_ws, size_t ws_size,
                              hipStream_t stream) {
    const float* x   = (const float*)d_in[0];
    const float* W1  = (const float*)d_in[1];
    const float* as1 = (const float*)d_in[2];
    const float* ad1 = (const float*)d_in[3];
    const float* b1  = (const float*)d_in[4];
    const float* g1  = (const float*)d_in[5];
    const float* be1 = (const float*)d_in[6];
    const float* W2  = (const float*)d_in[7];
    const float* as2 = (const float*)d_in[8];
    const float* ad2 = (const float*)d_in[9];
    const float* b2  = (const float*)d_in[10];
    const float* g2  = (const float*)d_in[11];
    const float* be2 = (const float*)d_in[12];
    const float* Wf  = (const float*)d_in[13];
    const float* bf  = (const float*)d_in[14];
    const int*   ei  = (const int*)d_in[15];
    const int* src = ei;
    const int* dst = ei + NE;
    float* out = (float*)d_out;

    float* ws = (float*)d_ws;
    float* CB1 = ws;                          // [N,192] layer-1 aggregate
    float* CB2 = CB1 + (size_t)NN * DD;       // [N,192] layer-2 aggregate
    float* AS  = CB2 + (size_t)NN * DD;       // [N,3]
    float* AD  = AS  + (size_t)NN * NH;       // [N,3]
    float* S1  = AD  + (size_t)NN * NH;       // [192]
    float* S2  = S1 + DD;
    float* SC1 = S2 + DD;
    float* SH1 = SC1 + DD;
    float* SC2 = SH1 + DD;
    float* SH2 = SC2 + DD;
    int* DEG    = (int*)(SH2 + DD);           // [N]
    int* ROWPTR = DEG + NN;                   // [N+1]
    int* CURSOR = ROWPTR + NN + 1;            // [N]
    int* BSUM   = CURSOR + NN;                // [NB]
    int* BOFF   = BSUM + NB;                  // [NB]
    int* CSRS   = BOFF + NB;                  // [E]
    unsigned short* R    = (unsigned short*)(CSRS + NE);
    unsigned short* Abf  = R;                          // [N,192] bf16 features
    unsigned short* Xh   = Abf + (size_t)NN * DD;      // [N,256]
    unsigned short* Xl   = Xh + (size_t)NN * DIN;
    unsigned short* W1hT = Xl + (size_t)NN * DIN;      // [192,256]
    unsigned short* W1lT = W1hT + DIN * DD;
    unsigned short* W2hT = W1lT + DIN * DD;            // [192,192]
    unsigned short* W2lT = W2hT + DD * DD;
    unsigned short* WfhT = W2lT + DD * DD;             // [64,192]
    unsigned short* WflT = WfhT + DD * DF;

    const int edge_grid = (NE + 255) / 256;
    const int gemm_grid = (NN + 63) / 64;
    const int gat_grid  = (NN + 3) / 4;
    const int bns_grid  = (NN + 127) / 128;

    // ---- CSR build (once) ----
    hipMemsetAsync(DEG, 0, (size_t)NN * 4, stream);
    hist_kernel<<<edge_grid, 256, 0, stream>>>(dst, DEG, NE);
    blocksum_kernel<<<NB, 256, 0, stream>>>(DEG, BSUM);
    scan_bsums<<<1, 256, 0, stream>>>(BSUM, BOFF, ROWPTR);
    expand_kernel<<<NB, 256, 0, stream>>>(DEG, BOFF, ROWPTR, CURSOR);
    scatter_kernel<<<edge_grid, 256, 0, stream>>>(src, dst, CURSOR, CSRS, NE);

    // ---- weight + input splits ----
    split_x<<<(NN * DIN / 4 + 255) / 256, 256, 0, stream>>>(x, Xh, Xl, NN * DIN);
    wsplit_T<DIN, DD><<<(DIN * DD + 255) / 256, 256, 0, stream>>>(W1, W1hT, W1lT);
    wsplit_T<DD, DD><<<(DD * DD + 255) / 256, 256, 0, stream>>>(W2, W2hT, W2lT);
    wsplit_T<DD, DF><<<(DD * DF + 255) / 256, 256, 0, stream>>>(Wf, WfhT, WflT);

    // ================= layer 1 =================
    mfma_gemm<DIN, DD, 0><<<gemm_grid, 256, 0, stream>>>(
        Xh, Xl, nullptr, nullptr, nullptr, nullptr, nullptr, nullptr, nullptr, nullptr,
        W1hT, W1lT, nullptr, nullptr, Abf, NN);
    attn_dots<<<NN, 192, 0, stream>>>(Abf, as1, ad1, AS, AD);
    gat_gather<<<gat_grid, 256, 0, stream>>>(Abf, AS, AD, ROWPTR, CSRS, CB1);
    hipMemsetAsync(S1, 0, 2 * DD * 4, stream);
    bn_stats<<<bns_grid, 192, 0, stream>>>(CB1, b1, S1, S2, NN);
    bn_finalize<<<1, DD, 0, stream>>>(S1, S2, g1, be1, SC1, SH1, 1.0f / NN);

    // ================= layer 2 (BN1 fused into GEMM A-load) =================
    mfma_gemm<DD, DD, 1><<<gemm_grid, 256, 0, stream>>>(
        nullptr, nullptr, CB1, b1, SC1, SH1, nullptr, nullptr, nullptr, nullptr,
        W2hT, W2lT, nullptr, nullptr, Abf, NN);
    attn_dots<<<NN, 192, 0, stream>>>(Abf, as2, ad2, AS, AD);
    gat_gather<<<gat_grid, 256, 0, stream>>>(Abf, AS, AD, ROWPTR, CSRS, CB2);
    hipMemsetAsync(S1, 0, 2 * DD * 4, stream);
    bn_stats<<<bns_grid, 192, 0, stream>>>(CB2, b2, S1, S2, NN);
    bn_finalize<<<1, DD, 0, stream>>>(S1, S2, g2, be2, SC2, SH2, 1.0f / NN);

    // ============ final: out = (bn1(h1) + bn2(h2)) @ Wf + bf (all fused) ============
    mfma_gemm<DD, DF, 2><<<gemm_grid, 256, 0, stream>>>(
        nullptr, nullptr, CB1, b1, SC1, SH1, CB2, b2, SC2, SH2,
        WfhT, WflT, bf, out, nullptr, NN);
}

// Round 6
// 557.956 us; speedup vs baseline: 1.4470x; 1.0676x over previous
//
#include <hip/hip_runtime.h>

#define NN 50000
#define NE 800000
#define DIN 256
#define NH 3
#define HC 64
#define DD 192
#define DF 64
#define NB 196   // (NN + 255) / 256

typedef __attribute__((ext_vector_type(8))) short s8bf;   // 8 bf16 bit-patterns
typedef __attribute__((ext_vector_type(4))) float f32x4;

// ---- fp32 -> bf16 helpers ----
__device__ __forceinline__ unsigned short f2bf(float f) {
    unsigned u = __float_as_uint(f);
    unsigned r = u + 0x7fffu + ((u >> 16) & 1u);   // round-to-nearest-even
    return (unsigned short)(r >> 16);
}
__device__ __forceinline__ float bf2f(unsigned short h) {
    return __uint_as_float(((unsigned)h) << 16);
}
__device__ __forceinline__ void split2(float f, unsigned short& h, unsigned short& l) {
    h = f2bf(f);
    l = f2bf(f - bf2f(h));
}

// ---- split X [n*K] fp32 -> Xh, Xl bf16 ----
__global__ __launch_bounds__(256)
void split_x(const float* __restrict__ X, unsigned short* __restrict__ Xh,
             unsigned short* __restrict__ Xl, int total) {
    int i = (blockIdx.x * 256 + threadIdx.x) * 4;
    if (i >= total) return;
    float4 v = *(const float4*)(X + i);
    ushort4 h, l;
    split2(v.x, h.x, l.x); split2(v.y, h.y, l.y);
    split2(v.z, h.z, l.z); split2(v.w, h.w, l.w);
    *(ushort4*)(Xh + i) = h;
    *(ushort4*)(Xl + i) = l;
}

// ---- split + transpose W [K,D] fp32 -> WhT, WlT [D,K] bf16 ----
template<int K, int D>
__global__ __launch_bounds__(256)
void wsplit_T(const float* __restrict__ W, unsigned short* __restrict__ WhT,
              unsigned short* __restrict__ WlT) {
    int idx = blockIdx.x * 256 + threadIdx.x;
    if (idx >= K * D) return;
    int k = idx / D, d = idx - k * D;
    unsigned short h, l;
    split2(W[idx], h, l);
    WhT[d * K + k] = h;
    WlT[d * K + k] = l;
}

// ---- split-bf16 MFMA GEMM: block = 64 rows x DOUT; wave = 64 rows x DOUT/4 ----
template<int K, int DOUT, bool OUTF32>
__global__ __launch_bounds__(256)
void mfma_gemm(const unsigned short* __restrict__ Ah, const unsigned short* __restrict__ Al,
               const unsigned short* __restrict__ BhT, const unsigned short* __restrict__ BlT,
               const float* __restrict__ obias, float* __restrict__ Yf,
               unsigned short* __restrict__ Yb, int n) {
    constexpr int NT = DOUT / 64;            // 16-col tiles per wave
    const int wave = threadIdx.x >> 6, lane = threadIdx.x & 63;
    const int r = lane & 15, kg = lane >> 4;
    const int row0 = blockIdx.x * 64;
    const int col0 = wave * (DOUT / 4);

    f32x4 acc[4][NT] = {};

    size_t aoff[4];
#pragma unroll
    for (int g = 0; g < 4; ++g)
        aoff[g] = (size_t)min(row0 + g * 16 + r, n - 1) * K + kg * 8;
    size_t boff[NT];
#pragma unroll
    for (int t = 0; t < NT; ++t)
        boff[t] = (size_t)(col0 + t * 16 + r) * K + kg * 8;

    for (int k0 = 0; k0 < K; k0 += 32) {
        s8bf ah[4], al[4], bh[NT], bl[NT];
#pragma unroll
        for (int g = 0; g < 4; ++g) {
            ah[g] = *(const s8bf*)(Ah + aoff[g] + k0);
            al[g] = *(const s8bf*)(Al + aoff[g] + k0);
        }
#pragma unroll
        for (int t = 0; t < NT; ++t) {
            bh[t] = *(const s8bf*)(BhT + boff[t] + k0);
            bl[t] = *(const s8bf*)(BlT + boff[t] + k0);
        }
#pragma unroll
        for (int g = 0; g < 4; ++g)
#pragma unroll
            for (int t = 0; t < NT; ++t) {
                acc[g][t] = __builtin_amdgcn_mfma_f32_16x16x32_bf16(ah[g], bh[t], acc[g][t], 0, 0, 0);
                acc[g][t] = __builtin_amdgcn_mfma_f32_16x16x32_bf16(ah[g], bl[t], acc[g][t], 0, 0, 0);
                acc[g][t] = __builtin_amdgcn_mfma_f32_16x16x32_bf16(al[g], bh[t], acc[g][t], 0, 0, 0);
            }
    }

    // C layout: col = lane&15 (within tile), row = (lane>>4)*4 + reg
#pragma unroll
    for (int t = 0; t < NT; ++t) {
        int col = col0 + t * 16 + r;
        float b = OUTF32 ? obias[col] : 0.f;
#pragma unroll
        for (int g = 0; g < 4; ++g) {
#pragma unroll
            for (int rr = 0; rr < 4; ++rr) {
                int row = row0 + g * 16 + kg * 4 + rr;
                if (row < n) {
                    if constexpr (OUTF32)
                        Yf[(size_t)row * DOUT + col] = acc[g][t][rr] + b;
                    else
                        Yb[(size_t)row * DOUT + col] = f2bf(acc[g][t][rr]);
                }
            }
        }
    }
}

// ---- per-node attention dots (bf16 features) ----
__global__ __launch_bounds__(192)
void attn_dots(const unsigned short* __restrict__ xf,
               const float* __restrict__ att_s, const float* __restrict__ att_d,
               float* __restrict__ as_, float* __restrict__ ad_) {
    int nidx = blockIdx.x;
    int h = threadIdx.x >> 6;
    int lane = threadIdx.x & 63;
    float v = bf2f(xf[(size_t)nidx * DD + h * HC + lane]);
    float s = v * att_s[h * HC + lane];
    float d = v * att_d[h * HC + lane];
#pragma unroll
    for (int off = 32; off; off >>= 1) {
        s += __shfl_down(s, off);
        d += __shfl_down(d, off);
    }
    if (lane == 0) {
        as_[nidx * NH + h] = s;
        ad_[nidx * NH + h] = d;
    }
}

// ============ CSR build ============
__global__ void hist_kernel(const int* __restrict__ dst, int* __restrict__ deg, int ne) {
    int e = blockIdx.x * blockDim.x + threadIdx.x;
    if (e < ne) atomicAdd(&deg[dst[e]], 1);
}

__global__ __launch_bounds__(256)
void blocksum_kernel(const int* __restrict__ deg, int* __restrict__ bsum) {
    int i = blockIdx.x * 256 + threadIdx.x;
    int v = (i < NN) ? deg[i] : 0;
#pragma unroll
    for (int off = 32; off; off >>= 1) v += __shfl_down(v, off);
    __shared__ int ws[4];
    if ((threadIdx.x & 63) == 0) ws[threadIdx.x >> 6] = v;
    __syncthreads();
    if (threadIdx.x == 0) bsum[blockIdx.x] = ws[0] + ws[1] + ws[2] + ws[3];
}

__global__ __launch_bounds__(256)
void scan_bsums(const int* __restrict__ bsum, int* __restrict__ boff,
                int* __restrict__ rowptr) {
    __shared__ int s[256];
    int t = threadIdx.x;
    int v = (t < NB) ? bsum[t] : 0;
    s[t] = v;
    __syncthreads();
    for (int off = 1; off < 256; off <<= 1) {
        int u = (t >= off) ? s[t - off] : 0;
        __syncthreads();
        s[t] += u;
        __syncthreads();
    }
    if (t < NB) boff[t] = s[t] - v;
    if (t == 255) rowptr[NN] = s[255];
}

__global__ __launch_bounds__(256)
void expand_kernel(const int* __restrict__ deg, const int* __restrict__ boff,
                   int* __restrict__ rowptr, int* __restrict__ cursor) {
    __shared__ int s[256];
    int t = threadIdx.x;
    int i = blockIdx.x * 256 + t;
    int v = (i < NN) ? deg[i] : 0;
    s[t] = v;
    __syncthreads();
    for (int off = 1; off < 256; off <<= 1) {
        int u = (t >= off) ? s[t - off] : 0;
        __syncthreads();
        s[t] += u;
        __syncthreads();
    }
    if (i < NN) {
        int excl = s[t] - v + boff[blockIdx.x];
        rowptr[i] = excl;
        cursor[i] = excl;
    }
}

__global__ void scatter_kernel(const int* __restrict__ src, const int* __restrict__ dst,
                               int* __restrict__ cursor, int* __restrict__ csr_src,
                               int* __restrict__ csr_dst, int ne) {
    int e = blockIdx.x * blockDim.x + threadIdx.x;
    if (e >= ne) return;
    int d = dst[e];
    int pos = atomicAdd(&cursor[d], 1);
    csr_src[pos] = src[e];
    csr_dst[pos] = d;
}

// ---- edge-parallel: ew[i][h] = exp(leaky(as[s]+ad[d])) in CSR order ----
__global__ __launch_bounds__(256)
void edge_w(const int* __restrict__ csr_src, const int* __restrict__ csr_dst,
            const float* __restrict__ as_, const float* __restrict__ ad_,
            float* __restrict__ ew, int ne) {
    int i = blockIdx.x * 256 + threadIdx.x;
    if (i >= ne) return;
    int s = csr_src[i], d = csr_dst[i];
#pragma unroll
    for (int h = 0; h < NH; ++h) {
        float e = as_[s * NH + h] + ad_[d * NH + h];
        e = e > 0.f ? e : 0.2f * e;
        ew[(size_t)i * NH + h] = __expf(e);
    }
}

// ============ GAT gather: weighted aggregate (weights precomputed) ============
// one wave per dst node; lane owns channels {lane, lane+64, lane+128}; bf16 feats
__global__ __launch_bounds__(256)
void gat_gather(const unsigned short* __restrict__ xf,
                const float* __restrict__ ew,
                const int* __restrict__ rowptr, const int* __restrict__ csr_src,
                float* __restrict__ outp) {
    int d = blockIdx.x * 4 + (threadIdx.x >> 6);
    if (d >= NN) return;
    int lane = threadIdx.x & 63;
    int beg = rowptr[d], end = rowptr[d + 1];

    float a0 = 0.f, a1 = 0.f, a2 = 0.f;
    float den0 = 0.f, den1 = 0.f, den2 = 0.f;
    int i = beg;
    for (; i + 1 < end; i += 2) {
        int s0 = __builtin_amdgcn_readfirstlane(csr_src[i]);
        int s1 = __builtin_amdgcn_readfirstlane(csr_src[i + 1]);
        float w00 = ew[(size_t)i * NH + 0], w01 = ew[(size_t)i * NH + 1], w02 = ew[(size_t)i * NH + 2];
        float w10 = ew[(size_t)(i + 1) * NH + 0], w11 = ew[(size_t)(i + 1) * NH + 1], w12 = ew[(size_t)(i + 1) * NH + 2];
        const unsigned short* x0 = xf + (size_t)s0 * DD;
        const unsigned short* x1 = xf + (size_t)s1 * DD;
        float f00 = bf2f(x0[lane]), f01 = bf2f(x0[64 + lane]), f02 = bf2f(x0[128 + lane]);
        float f10 = bf2f(x1[lane]), f11 = bf2f(x1[64 + lane]), f12 = bf2f(x1[128 + lane]);
        den0 += w00 + w10; den1 += w01 + w11; den2 += w02 + w12;
        a0 = fmaf(f00, w00, a0); a0 = fmaf(f10, w10, a0);
        a1 = fmaf(f01, w01, a1); a1 = fmaf(f11, w11, a1);
        a2 = fmaf(f02, w02, a2); a2 = fmaf(f12, w12, a2);
    }
    if (i < end) {
        int s0 = __builtin_amdgcn_readfirstlane(csr_src[i]);
        float w00 = ew[(size_t)i * NH + 0], w01 = ew[(size_t)i * NH + 1], w02 = ew[(size_t)i * NH + 2];
        const unsigned short* x0 = xf + (size_t)s0 * DD;
        den0 += w00; den1 += w01; den2 += w02;
        a0 = fmaf(bf2f(x0[lane]),       w00, a0);
        a1 = fmaf(bf2f(x0[64 + lane]),  w01, a1);
        a2 = fmaf(bf2f(x0[128 + lane]), w02, a2);
    }
    size_t o = (size_t)d * DD + lane;
    outp[o]       = a0 / (den0 + 1e-16f);
    outp[o + 64]  = a1 / (den1 + 1e-16f);
    outp[o + 128] = a2 / (den2 + 1e-16f);
}

// ---- BN pass 1: per-feature sum / sumsq of relu(h + bias) ----
__global__ __launch_bounds__(192)
void bn_stats(const float* __restrict__ hbuf, const float* __restrict__ bias,
              float* __restrict__ s1, float* __restrict__ s2, int n) {
    int j = threadIdx.x;
    float b = bias[j];
    int r0 = blockIdx.x * 128;
    int r1 = min(r0 + 128, n);
    float a = 0.f, q = 0.f;
    for (int r = r0; r < r1; ++r) {
        float v = hbuf[(size_t)r * DD + j] + b;
        v = fmaxf(v, 0.f);
        a += v; q += v * v;
    }
    atomicAdd(&s1[j], a);
    atomicAdd(&s2[j], q);
}

__global__ void bn_finalize(const float* __restrict__ s1, const float* __restrict__ s2,
                            const float* __restrict__ g, const float* __restrict__ beta,
                            float* __restrict__ scale, float* __restrict__ shift, float invn) {
    int j = threadIdx.x;
    float mu = s1[j] * invn;
    float var = s2[j] * invn - mu * mu;
    float sc = g[j] * rsqrtf(var + 1e-5f);
    scale[j] = sc;
    shift[j] = beta[j] - mu * sc;
}

// ---- BN apply: y = bn(relu(in+bias)) -> bf16 hi/lo ----
__global__ __launch_bounds__(256)
void bn_apply_split(const float* __restrict__ in, const float* __restrict__ bias,
                    const float* __restrict__ scale, const float* __restrict__ shift,
                    unsigned short* __restrict__ oh, unsigned short* __restrict__ ol, int total) {
    int i = (blockIdx.x * 256 + threadIdx.x) * 4;
    if (i >= total) return;
    int j = i % DD;
    float4 v = *(const float4*)(in + i);
    float4 b = *(const float4*)(bias + j);
    float4 sc = *(const float4*)(scale + j);
    float4 sh = *(const float4*)(shift + j);
    float4 y;
    y.x = fmaxf(v.x + b.x, 0.f) * sc.x + sh.x;
    y.y = fmaxf(v.y + b.y, 0.f) * sc.y + sh.y;
    y.z = fmaxf(v.z + b.z, 0.f) * sc.z + sh.z;
    y.w = fmaxf(v.w + b.w, 0.f) * sc.w + sh.w;
    ushort4 h, l;
    split2(y.x, h.x, l.x); split2(y.y, h.y, l.y);
    split2(y.z, h.z, l.z); split2(y.w, h.w, l.w);
    *(ushort4*)(oh + i) = h;
    *(ushort4*)(ol + i) = l;
}

// ---- BN apply-sum: y = bn1(relu(C1+b1)) + bn2(relu(C2+b2)) -> bf16 hi/lo ----
__global__ __launch_bounds__(256)
void bn_apply_sum2(const float* __restrict__ C1, const float* __restrict__ b1,
                   const float* __restrict__ sc1, const float* __restrict__ sh1,
                   const float* __restrict__ C2, const float* __restrict__ b2,
                   const float* __restrict__ sc2, const float* __restrict__ sh2,
                   unsigned short* __restrict__ oh, unsigned short* __restrict__ ol, int total) {
    int i = (blockIdx.x * 256 + threadIdx.x) * 4;
    if (i >= total) return;
    int j = i % DD;
    float4 v1 = *(const float4*)(C1 + i);
    float4 v2 = *(const float4*)(C2 + i);
    float4 a1 = *(const float4*)(b1 + j),  s1v = *(const float4*)(sc1 + j), h1v = *(const float4*)(sh1 + j);
    float4 a2 = *(const float4*)(b2 + j),  s2v = *(const float4*)(sc2 + j), h2v = *(const float4*)(sh2 + j);
    float4 y;
    y.x = fmaxf(v1.x + a1.x, 0.f) * s1v.x + h1v.x + fmaxf(v2.x + a2.x, 0.f) * s2v.x + h2v.x;
    y.y = fmaxf(v1.y + a1.y, 0.f) * s1v.y + h1v.y + fmaxf(v2.y + a2.y, 0.f) * s2v.y + h2v.y;
    y.z = fmaxf(v1.z + a1.z, 0.f) * s1v.z + h1v.z + fmaxf(v2.z + a2.z, 0.f) * s2v.z + h2v.z;
    y.w = fmaxf(v1.w + a1.w, 0.f) * s1v.w + h1v.w + fmaxf(v2.w + a2.w, 0.f) * s2v.w + h2v.w;
    ushort4 h, l;
    split2(y.x, h.x, l.x); split2(y.y, h.y, l.y);
    split2(y.z, h.z, l.z); split2(y.w, h.w, l.w);
    *(ushort4*)(oh + i) = h;
    *(ushort4*)(ol + i) = l;
}

extern "C" void kernel_launch(void* const* d_in, const int* in_sizes, int n_in,
                              void* d_out, int out_size, void* d_ws, size_t ws_size,
                              hipStream_t stream) {
    const float* x   = (const float*)d_in[0];
    const float* W1  = (const float*)d_in[1];
    const float* as1 = (const float*)d_in[2];
    const float* ad1 = (const float*)d_in[3];
    const float* b1  = (const float*)d_in[4];
    const float* g1  = (const float*)d_in[5];
    const float* be1 = (const float*)d_in[6];
    const float* W2  = (const float*)d_in[7];
    const float* as2 = (const float*)d_in[8];
    const float* ad2 = (const float*)d_in[9];
    const float* b2  = (const float*)d_in[10];
    const float* g2  = (const float*)d_in[11];
    const float* be2 = (const float*)d_in[12];
    const float* Wf  = (const float*)d_in[13];
    const float* bf  = (const float*)d_in[14];
    const int*   ei  = (const int*)d_in[15];
    const int* src = ei;
    const int* dst = ei + NE;
    float* out = (float*)d_out;

    float* ws = (float*)d_ws;
    float* CB1 = ws;                          // [N,192]
    float* CB2 = CB1 + (size_t)NN * DD;       // [N,192]
    float* AS  = CB2 + (size_t)NN * DD;       // [N,3]
    float* AD  = AS  + (size_t)NN * NH;       // [N,3]
    float* EW  = AD  + (size_t)NN * NH;       // [E,3] CSR-ordered weights
    float* S1  = EW  + (size_t)NE * NH;       // [192]
    float* S2  = S1 + DD;
    float* SC1 = S2 + DD;
    float* SH1 = SC1 + DD;
    float* SC2 = SH1 + DD;
    float* SH2 = SC2 + DD;
    int* DEG    = (int*)(SH2 + DD);           // [N]
    int* ROWPTR = DEG + NN;                   // [N+1]
    int* CURSOR = ROWPTR + NN + 1;            // [N]
    int* BSUM   = CURSOR + NN;                // [NB]
    int* BOFF   = BSUM + NB;                  // [NB]
    int* CSRS   = BOFF + NB;                  // [E]
    int* CSRD   = CSRS + NE;                  // [E]
    unsigned short* R    = (unsigned short*)(CSRD + NE);
    unsigned short* Abf  = R;                          // [N,192] bf16 features
    unsigned short* Xh   = Abf + (size_t)NN * DD;      // [N,256] -> later Hh/Sh
    unsigned short* Xl   = Xh + (size_t)NN * DIN;      // [N,256] -> later Hl/Sl
    unsigned short* Hh   = Xh;
    unsigned short* Hl   = Xl;
    unsigned short* Sh   = Xh;
    unsigned short* Sl   = Xl;
    unsigned short* W1hT = Xl + (size_t)NN * DIN;      // [192,256]
    unsigned short* W1lT = W1hT + DIN * DD;
    unsigned short* W2hT = W1lT + DIN * DD;            // [192,192]
    unsigned short* W2lT = W2hT + DD * DD;
    unsigned short* WfhT = W2lT + DD * DD;             // [64,192]
    unsigned short* WflT = WfhT + DD * DF;

    const int edge_grid = (NE + 255) / 256;
    const int gemm_grid = (NN + 63) / 64;
    const int gat_grid  = (NN + 3) / 4;
    const int bns_grid  = (NN + 127) / 128;
    const int bna_grid  = (NN * DD / 4 + 255) / 256;

    // ---- CSR build (once) ----
    hipMemsetAsync(DEG, 0, (size_t)NN * 4, stream);
    hist_kernel<<<edge_grid, 256, 0, stream>>>(dst, DEG, NE);
    blocksum_kernel<<<NB, 256, 0, stream>>>(DEG, BSUM);
    scan_bsums<<<1, 256, 0, stream>>>(BSUM, BOFF, ROWPTR);
    expand_kernel<<<NB, 256, 0, stream>>>(DEG, BOFF, ROWPTR, CURSOR);
    scatter_kernel<<<edge_grid, 256, 0, stream>>>(src, dst, CURSOR, CSRS, CSRD, NE);

    // ---- weight + input splits ----
    split_x<<<(NN * DIN / 4 + 255) / 256, 256, 0, stream>>>(x, Xh, Xl, NN * DIN);
    wsplit_T<DIN, DD><<<(DIN * DD + 255) / 256, 256, 0, stream>>>(W1, W1hT, W1lT);
    wsplit_T<DD, DD><<<(DD * DD + 255) / 256, 256, 0, stream>>>(W2, W2hT, W2lT);
    wsplit_T<DD, DF><<<(DD * DF + 255) / 256, 256, 0, stream>>>(Wf, WfhT, WflT);

    // ================= layer 1 =================
    mfma_gemm<DIN, DD, false><<<gemm_grid, 256, 0, stream>>>(
        Xh, Xl, W1hT, W1lT, nullptr, nullptr, Abf, NN);
    attn_dots<<<NN, 192, 0, stream>>>(Abf, as1, ad1, AS, AD);
    edge_w<<<edge_grid, 256, 0, stream>>>(CSRS, CSRD, AS, AD, EW, NE);
    gat_gather<<<gat_grid, 256, 0, stream>>>(Abf, EW, ROWPTR, CSRS, CB1);
    hipMemsetAsync(S1, 0, 2 * DD * 4, stream);
    bn_stats<<<bns_grid, 192, 0, stream>>>(CB1, b1, S1, S2, NN);
    bn_finalize<<<1, DD, 0, stream>>>(S1, S2, g1, be1, SC1, SH1, 1.0f / NN);
    bn_apply_split<<<bna_grid, 256, 0, stream>>>(CB1, b1, SC1, SH1, Hh, Hl, NN * DD);

    // ================= layer 2 =================
    mfma_gemm<DD, DD, false><<<gemm_grid, 256, 0, stream>>>(
        Hh, Hl, W2hT, W2lT, nullptr, nullptr, Abf, NN);
    attn_dots<<<NN, 192, 0, stream>>>(Abf, as2, ad2, AS, AD);
    edge_w<<<edge_grid, 256, 0, stream>>>(CSRS, CSRD, AS, AD, EW, NE);
    gat_gather<<<gat_grid, 256, 0, stream>>>(Abf, EW, ROWPTR, CSRS, CB2);
    hipMemsetAsync(S1, 0, 2 * DD * 4, stream);
    bn_stats<<<bns_grid, 192, 0, stream>>>(CB2, b2, S1, S2, NN);
    bn_finalize<<<1, DD, 0, stream>>>(S1, S2, g2, be2, SC2, SH2, 1.0f / NN);
    bn_apply_sum2<<<bna_grid, 256, 0, stream>>>(CB1, b1, SC1, SH1, CB2, b2, SC2, SH2,
                                                Sh, Sl, NN * DD);

    // ================= final: out = (bn1(h1) + bn2(h2)) @ Wf + bf =================
    mfma_gemm<DD, DF, true><<<gemm_grid, 256, 0, stream>>>(
        Sh, Sl, WfhT, WflT, bf, out, nullptr, NN);
}

// Round 7
// 544.416 us; speedup vs baseline: 1.4830x; 1.0249x over previous
//
#include <hip/hip_runtime.h>

#define NN 50000
#define NE 800000
#define DIN 256
#define NH 3
#define HC 64
#define DD 192
#define DF 64
#define NB 196   // (NN + 255) / 256

typedef __attribute__((ext_vector_type(8))) short s8bf;   // 8 bf16 bit-patterns
typedef __attribute__((ext_vector_type(4))) float f32x4;

// ---- fp32 -> bf16 helpers ----
__device__ __forceinline__ unsigned short f2bf(float f) {
    unsigned u = __float_as_uint(f);
    unsigned r = u + 0x7fffu + ((u >> 16) & 1u);   // round-to-nearest-even
    return (unsigned short)(r >> 16);
}
__device__ __forceinline__ float bf2f(unsigned short h) {
    return __uint_as_float(((unsigned)h) << 16);
}
__device__ __forceinline__ void split2(float f, unsigned short& h, unsigned short& l) {
    h = f2bf(f);
    l = f2bf(f - bf2f(h));
}

// ---- split X [n*K] fp32 -> Xh, Xl bf16 ----
__global__ __launch_bounds__(256)
void split_x(const float* __restrict__ X, unsigned short* __restrict__ Xh,
             unsigned short* __restrict__ Xl, int total) {
    int i = (blockIdx.x * 256 + threadIdx.x) * 4;
    if (i >= total) return;
    float4 v = *(const float4*)(X + i);
    ushort4 h, l;
    split2(v.x, h.x, l.x); split2(v.y, h.y, l.y);
    split2(v.z, h.z, l.z); split2(v.w, h.w, l.w);
    *(ushort4*)(Xh + i) = h;
    *(ushort4*)(Xl + i) = l;
}

// ---- split + transpose all three weights in one dispatch ----
#define W1N (DIN * DD)           // 49152
#define W2N (DD * DD)            // 36864
#define WFN (DD * DF)            // 12288
__global__ __launch_bounds__(256)
void wsplit_all(const float* __restrict__ W1, const float* __restrict__ W2,
                const float* __restrict__ Wf,
                unsigned short* __restrict__ W1hT, unsigned short* __restrict__ W1lT,
                unsigned short* __restrict__ W2hT, unsigned short* __restrict__ W2lT,
                unsigned short* __restrict__ WfhT, unsigned short* __restrict__ WflT) {
    int idx = blockIdx.x * 256 + threadIdx.x;
    const float* W; unsigned short *Wh, *Wl; int K, D, base;
    if (idx < W1N)              { W = W1; Wh = W1hT; Wl = W1lT; K = DIN; D = DD; base = idx; }
    else if (idx < W1N + W2N)   { W = W2; Wh = W2hT; Wl = W2lT; K = DD;  D = DD; base = idx - W1N; }
    else if (idx < W1N + W2N + WFN) { W = Wf; Wh = WfhT; Wl = WflT; K = DD; D = DF; base = idx - W1N - W2N; }
    else return;
    int k = base / D, d = base - k * D;
    unsigned short h, l;
    split2(W[base], h, l);
    Wh[d * K + k] = h;
    Wl[d * K + k] = l;
}

// ---- split-bf16 MFMA GEMM: block = 128 rows x DOUT; wave = 128 rows x DOUT/4 ----
template<int K, int DOUT, bool OUTF32>
__global__ __launch_bounds__(256)
void mfma_gemm(const unsigned short* __restrict__ Ah, const unsigned short* __restrict__ Al,
               const unsigned short* __restrict__ BhT, const unsigned short* __restrict__ BlT,
               const float* __restrict__ obias, float* __restrict__ Yf,
               unsigned short* __restrict__ Yb, int n) {
    constexpr int NT = DOUT / 64;            // 16-col tiles per wave
    const int wave = threadIdx.x >> 6, lane = threadIdx.x & 63;
    const int r = lane & 15, kg = lane >> 4;
    const int row0 = blockIdx.x * 128;
    const int col0 = wave * (DOUT / 4);

    f32x4 acc[8][NT] = {};

    int aoff[8];
#pragma unroll
    for (int g = 0; g < 8; ++g)
        aoff[g] = min(row0 + g * 16 + r, n - 1) * K + kg * 8;
    int boff[NT];
#pragma unroll
    for (int t = 0; t < NT; ++t)
        boff[t] = (col0 + t * 16 + r) * K + kg * 8;

    for (int k0 = 0; k0 < K; k0 += 32) {
        s8bf ah[8], al[8], bh[NT], bl[NT];
#pragma unroll
        for (int t = 0; t < NT; ++t) {
            bh[t] = *(const s8bf*)(BhT + boff[t] + k0);
            bl[t] = *(const s8bf*)(BlT + boff[t] + k0);
        }
#pragma unroll
        for (int g = 0; g < 8; ++g) {
            ah[g] = *(const s8bf*)(Ah + aoff[g] + k0);
            al[g] = *(const s8bf*)(Al + aoff[g] + k0);
        }
#pragma unroll
        for (int g = 0; g < 8; ++g)
#pragma unroll
            for (int t = 0; t < NT; ++t) {
                acc[g][t] = __builtin_amdgcn_mfma_f32_16x16x32_bf16(ah[g], bh[t], acc[g][t], 0, 0, 0);
                acc[g][t] = __builtin_amdgcn_mfma_f32_16x16x32_bf16(ah[g], bl[t], acc[g][t], 0, 0, 0);
                acc[g][t] = __builtin_amdgcn_mfma_f32_16x16x32_bf16(al[g], bh[t], acc[g][t], 0, 0, 0);
            }
    }

    // C layout: col = lane&15 (within tile), row = (lane>>4)*4 + reg
#pragma unroll
    for (int t = 0; t < NT; ++t) {
        int col = col0 + t * 16 + r;
        float b = OUTF32 ? obias[col] : 0.f;
#pragma unroll
        for (int g = 0; g < 8; ++g) {
#pragma unroll
            for (int rr = 0; rr < 4; ++rr) {
                int row = row0 + g * 16 + kg * 4 + rr;
                if (row < n) {
                    if constexpr (OUTF32)
                        Yf[(size_t)row * DOUT + col] = acc[g][t][rr] + b;
                    else
                        Yb[(size_t)row * DOUT + col] = f2bf(acc[g][t][rr]);
                }
            }
        }
    }
}

// ---- per-node attention dots: one wave per node, 4 nodes/block ----
__global__ __launch_bounds__(256)
void attn_dots(const unsigned short* __restrict__ xf,
               const float* __restrict__ att_s, const float* __restrict__ att_d,
               float* __restrict__ as_, float* __restrict__ ad_) {
    int wid = blockIdx.x * 4 + (threadIdx.x >> 6);
    if (wid >= NN) return;
    int lane = threadIdx.x & 63;
    const unsigned short* xp = xf + (size_t)wid * DD;
    float v0 = bf2f(xp[lane]), v1 = bf2f(xp[64 + lane]), v2 = bf2f(xp[128 + lane]);
    float s0 = v0 * att_s[lane], s1 = v1 * att_s[64 + lane], s2 = v2 * att_s[128 + lane];
    float d0 = v0 * att_d[lane], d1 = v1 * att_d[64 + lane], d2 = v2 * att_d[128 + lane];
#pragma unroll
    for (int off = 32; off; off >>= 1) {
        s0 += __shfl_down(s0, off); s1 += __shfl_down(s1, off); s2 += __shfl_down(s2, off);
        d0 += __shfl_down(d0, off); d1 += __shfl_down(d1, off); d2 += __shfl_down(d2, off);
    }
    if (lane == 0) {
        as_[wid * NH + 0] = s0; as_[wid * NH + 1] = s1; as_[wid * NH + 2] = s2;
        ad_[wid * NH + 0] = d0; ad_[wid * NH + 1] = d1; ad_[wid * NH + 2] = d2;
    }
}

// ============ CSR build ============
__global__ void hist_kernel(const int* __restrict__ dst, int* __restrict__ deg, int ne) {
    int e = blockIdx.x * blockDim.x + threadIdx.x;
    if (e < ne) atomicAdd(&deg[dst[e]], 1);
}

__global__ __launch_bounds__(256)
void blocksum_kernel(const int* __restrict__ deg, int* __restrict__ bsum) {
    int i = blockIdx.x * 256 + threadIdx.x;
    int v = (i < NN) ? deg[i] : 0;
#pragma unroll
    for (int off = 32; off; off >>= 1) v += __shfl_down(v, off);
    __shared__ int ws[4];
    if ((threadIdx.x & 63) == 0) ws[threadIdx.x >> 6] = v;
    __syncthreads();
    if (threadIdx.x == 0) bsum[blockIdx.x] = ws[0] + ws[1] + ws[2] + ws[3];
}

__global__ __launch_bounds__(256)
void scan_bsums(const int* __restrict__ bsum, int* __restrict__ boff,
                int* __restrict__ rowptr) {
    __shared__ int s[256];
    int t = threadIdx.x;
    int v = (t < NB) ? bsum[t] : 0;
    s[t] = v;
    __syncthreads();
    for (int off = 1; off < 256; off <<= 1) {
        int u = (t >= off) ? s[t - off] : 0;
        __syncthreads();
        s[t] += u;
        __syncthreads();
    }
    if (t < NB) boff[t] = s[t] - v;
    if (t == 255) rowptr[NN] = s[255];
}

__global__ __launch_bounds__(256)
void expand_kernel(const int* __restrict__ deg, const int* __restrict__ boff,
                   int* __restrict__ rowptr, int* __restrict__ cursor) {
    __shared__ int s[256];
    int t = threadIdx.x;
    int i = blockIdx.x * 256 + t;
    int v = (i < NN) ? deg[i] : 0;
    s[t] = v;
    __syncthreads();
    for (int off = 1; off < 256; off <<= 1) {
        int u = (t >= off) ? s[t - off] : 0;
        __syncthreads();
        s[t] += u;
        __syncthreads();
    }
    if (i < NN) {
        int excl = s[t] - v + boff[blockIdx.x];
        rowptr[i] = excl;
        cursor[i] = excl;
    }
}

__global__ void scatter_kernel(const int* __restrict__ src, const int* __restrict__ dst,
                               int* __restrict__ cursor, int* __restrict__ csr_src,
                               int* __restrict__ csr_dst, int ne) {
    int e = blockIdx.x * blockDim.x + threadIdx.x;
    if (e >= ne) return;
    int d = dst[e];
    int pos = atomicAdd(&cursor[d], 1);
    csr_src[pos] = src[e];
    csr_dst[pos] = d;
}

// ---- edge-parallel: ew[i][h] = exp(leaky(as[s]+ad[d])) in CSR order ----
__global__ __launch_bounds__(256)
void edge_w(const int* __restrict__ csr_src, const int* __restrict__ csr_dst,
            const float* __restrict__ as_, const float* __restrict__ ad_,
            float* __restrict__ ew, int ne) {
    int i = blockIdx.x * 256 + threadIdx.x;
    if (i >= ne) return;
    int s = csr_src[i], d = csr_dst[i];
#pragma unroll
    for (int h = 0; h < NH; ++h) {
        float e = as_[s * NH + h] + ad_[d * NH + h];
        e = e > 0.f ? e : 0.2f * e;
        ew[(size_t)i * NH + h] = __expf(e);
    }
}

// ============ GAT gather: 2 waves per dst node (edge range split) ============
// lane owns channels {lane, lane+64, lane+128}; bf16 feats; weights precomputed
__global__ __launch_bounds__(256)
void gat_gather(const unsigned short* __restrict__ xf,
                const float* __restrict__ ew,
                const int* __restrict__ rowptr, const int* __restrict__ csr_src,
                float* __restrict__ outp) {
    __shared__ float lA[4][192];
    __shared__ float lD[4][3];
    const int wid  = threadIdx.x >> 6;        // 0..3
    const int pair = wid >> 1;                // 0,1: which node
    const int w    = wid & 1;                 // 0,1: which half of edge list
    const int lane = threadIdx.x & 63;
    const int d = blockIdx.x * 2 + pair;

    float a0 = 0.f, a1 = 0.f, a2 = 0.f;
    float den0 = 0.f, den1 = 0.f, den2 = 0.f;
    if (d < NN) {
        int beg = rowptr[d], end = rowptr[d + 1];
        int mid = beg + ((end - beg + 1) >> 1);
        int lo = w ? mid : beg;
        int hi = w ? end : mid;
        int i = lo;
        for (; i + 1 < hi; i += 2) {
            int s0 = __builtin_amdgcn_readfirstlane(csr_src[i]);
            int s1 = __builtin_amdgcn_readfirstlane(csr_src[i + 1]);
            float w00 = ew[(size_t)i * NH + 0], w01 = ew[(size_t)i * NH + 1], w02 = ew[(size_t)i * NH + 2];
            float w10 = ew[(size_t)(i + 1) * NH + 0], w11 = ew[(size_t)(i + 1) * NH + 1], w12 = ew[(size_t)(i + 1) * NH + 2];
            const unsigned short* x0 = xf + (size_t)s0 * DD;
            const unsigned short* x1 = xf + (size_t)s1 * DD;
            float f00 = bf2f(x0[lane]), f01 = bf2f(x0[64 + lane]), f02 = bf2f(x0[128 + lane]);
            float f10 = bf2f(x1[lane]), f11 = bf2f(x1[64 + lane]), f12 = bf2f(x1[128 + lane]);
            den0 += w00 + w10; den1 += w01 + w11; den2 += w02 + w12;
            a0 = fmaf(f00, w00, a0); a0 = fmaf(f10, w10, a0);
            a1 = fmaf(f01, w01, a1); a1 = fmaf(f11, w11, a1);
            a2 = fmaf(f02, w02, a2); a2 = fmaf(f12, w12, a2);
        }
        if (i < hi) {
            int s0 = __builtin_amdgcn_readfirstlane(csr_src[i]);
            float w00 = ew[(size_t)i * NH + 0], w01 = ew[(size_t)i * NH + 1], w02 = ew[(size_t)i * NH + 2];
            const unsigned short* x0 = xf + (size_t)s0 * DD;
            den0 += w00; den1 += w01; den2 += w02;
            a0 = fmaf(bf2f(x0[lane]),       w00, a0);
            a1 = fmaf(bf2f(x0[64 + lane]),  w01, a1);
            a2 = fmaf(bf2f(x0[128 + lane]), w02, a2);
        }
    }
    lA[wid][lane]       = a0;
    lA[wid][lane + 64]  = a1;
    lA[wid][lane + 128] = a2;
    if (lane == 0) { lD[wid][0] = den0; lD[wid][1] = den1; lD[wid][2] = den2; }
    __syncthreads();
    if (w == 0 && d < NN) {
        float dn0 = lD[wid][0] + lD[wid + 1][0];
        float dn1 = lD[wid][1] + lD[wid + 1][1];
        float dn2 = lD[wid][2] + lD[wid + 1][2];
        size_t o = (size_t)d * DD + lane;
        outp[o]       = (lA[wid][lane]       + lA[wid + 1][lane])       / (dn0 + 1e-16f);
        outp[o + 64]  = (lA[wid][lane + 64]  + lA[wid + 1][lane + 64])  / (dn1 + 1e-16f);
        outp[o + 128] = (lA[wid][lane + 128] + lA[wid + 1][lane + 128]) / (dn2 + 1e-16f);
    }
}

// ---- BN pass 1: per-feature sum / sumsq of relu(h + bias) ----
__global__ __launch_bounds__(192)
void bn_stats(const float* __restrict__ hbuf, const float* __restrict__ bias,
              float* __restrict__ s1, float* __restrict__ s2, int n) {
    int j = threadIdx.x;
    float b = bias[j];
    int r0 = blockIdx.x * 128;
    int r1 = min(r0 + 128, n);
    float a = 0.f, q = 0.f;
    for (int r = r0; r < r1; ++r) {
        float v = hbuf[(size_t)r * DD + j] + b;
        v = fmaxf(v, 0.f);
        a += v; q += v * v;
    }
    atomicAdd(&s1[j], a);
    atomicAdd(&s2[j], q);
}

// ---- BN apply (finalize inline): y = bn(relu(in+bias)) -> bf16 hi/lo ----
__global__ __launch_bounds__(256)
void bn_apply_split(const float* __restrict__ in, const float* __restrict__ bias,
                    const float* __restrict__ S1, const float* __restrict__ S2,
                    const float* __restrict__ g, const float* __restrict__ beta,
                    unsigned short* __restrict__ oh, unsigned short* __restrict__ ol, int total) {
    int i = (blockIdx.x * 256 + threadIdx.x) * 4;
    if (i >= total) return;
    int j = i % DD;
    const float invn = 1.0f / NN;
    float4 v = *(const float4*)(in + i);
    float vv[4] = {v.x, v.y, v.z, v.w};
    ushort4 h, l;
    unsigned short* hp = (unsigned short*)&h;
    unsigned short* lp = (unsigned short*)&l;
#pragma unroll
    for (int q = 0; q < 4; ++q) {
        float mu = S1[j + q] * invn;
        float var = S2[j + q] * invn - mu * mu;
        float sc = g[j + q] * rsqrtf(var + 1e-5f);
        float sh = beta[j + q] - mu * sc;
        float y = fmaxf(vv[q] + bias[j + q], 0.f) * sc + sh;
        split2(y, hp[q], lp[q]);
    }
    *(ushort4*)(oh + i) = h;
    *(ushort4*)(ol + i) = l;
}

// ---- BN apply-sum (finalize inline): y = bn1(relu(C1+b1)) + bn2(relu(C2+b2)) ----
__global__ __launch_bounds__(256)
void bn_apply_sum2(const float* __restrict__ C1, const float* __restrict__ b1,
                   const float* __restrict__ S1a, const float* __restrict__ S2a,
                   const float* __restrict__ g1, const float* __restrict__ be1,
                   const float* __restrict__ C2, const float* __restrict__ b2,
                   const float* __restrict__ S1b, const float* __restrict__ S2b,
                   const float* __restrict__ g2, const float* __restrict__ be2,
                   unsigned short* __restrict__ oh, unsigned short* __restrict__ ol, int total) {
    int i = (blockIdx.x * 256 + threadIdx.x) * 4;
    if (i >= total) return;
    int j = i % DD;
    const float invn = 1.0f / NN;
    float4 v1 = *(const float4*)(C1 + i);
    float4 v2 = *(const float4*)(C2 + i);
    float a1[4] = {v1.x, v1.y, v1.z, v1.w};
    float a2[4] = {v2.x, v2.y, v2.z, v2.w};
    ushort4 h, l;
    unsigned short* hp = (unsigned short*)&h;
    unsigned short* lp = (unsigned short*)&l;
#pragma unroll
    for (int q = 0; q < 4; ++q) {
        float mu1 = S1a[j + q] * invn;
        float var1 = S2a[j + q] * invn - mu1 * mu1;
        float sc1 = g1[j + q] * rsqrtf(var1 + 1e-5f);
        float sh1 = be1[j + q] - mu1 * sc1;
        float mu2 = S1b[j + q] * invn;
        float var2 = S2b[j + q] * invn - mu2 * mu2;
        float sc2 = g2[j + q] * rsqrtf(var2 + 1e-5f);
        float sh2 = be2[j + q] - mu2 * sc2;
        float y = fmaxf(a1[q] + b1[j + q], 0.f) * sc1 + sh1
                + fmaxf(a2[q] + b2[j + q], 0.f) * sc2 + sh2;
        split2(y, hp[q], lp[q]);
    }
    *(ushort4*)(oh + i) = h;
    *(ushort4*)(ol + i) = l;
}

extern "C" void kernel_launch(void* const* d_in, const int* in_sizes, int n_in,
                              void* d_out, int out_size, void* d_ws, size_t ws_size,
                              hipStream_t stream) {
    const float* x   = (const float*)d_in[0];
    const float* W1  = (const float*)d_in[1];
    const float* as1 = (const float*)d_in[2];
    const float* ad1 = (const float*)d_in[3];
    const float* b1  = (const float*)d_in[4];
    const float* g1  = (const float*)d_in[5];
    const float* be1 = (const float*)d_in[6];
    const float* W2  = (const float*)d_in[7];
    const float* as2 = (const float*)d_in[8];
    const float* ad2 = (const float*)d_in[9];
    const float* b2  = (const float*)d_in[10];
    const float* g2  = (const float*)d_in[11];
    const float* be2 = (const float*)d_in[12];
    const float* Wf  = (const float*)d_in[13];
    const float* bf  = (const float*)d_in[14];
    const int*   ei  = (const int*)d_in[15];
    const int* src = ei;
    const int* dst = ei + NE;
    float* out = (float*)d_out;

    float* ws = (float*)d_ws;
    float* CB1 = ws;                          // [N,192]
    float* CB2 = CB1 + (size_t)NN * DD;       // [N,192]
    float* AS  = CB2 + (size_t)NN * DD;       // [N,3]
    float* AD  = AS  + (size_t)NN * NH;       // [N,3]
    float* EW  = AD  + (size_t)NN * NH;       // [E,3] CSR-ordered weights
    int* DEG   = (int*)(EW + (size_t)NE * NH);// [N]     (zeroed together with stats)
    float* S1a = (float*)(DEG + NN);          // [192] x4 stats, contiguous after DEG
    float* S2a = S1a + DD;
    float* S1b = S2a + DD;
    float* S2b = S1b + DD;
    int* ROWPTR = (int*)(S2b + DD);           // [N+1]
    int* CURSOR = ROWPTR + NN + 1;            // [N]
    int* BSUM   = CURSOR + NN;                // [NB]
    int* BOFF   = BSUM + NB;                  // [NB]
    int* CSRS   = BOFF + NB;                  // [E]
    int* CSRD   = CSRS + NE;                  // [E]
    unsigned short* R    = (unsigned short*)(CSRD + NE);
    unsigned short* Abf  = R;                          // [N,192] bf16 features
    unsigned short* Xh   = Abf + (size_t)NN * DD;      // [N,256] -> later Hh/Sh
    unsigned short* Xl   = Xh + (size_t)NN * DIN;      // [N,256] -> later Hl/Sl
    unsigned short* Hh   = Xh;
    unsigned short* Hl   = Xl;
    unsigned short* Sh   = Xh;
    unsigned short* Sl   = Xl;
    unsigned short* W1hT = Xl + (size_t)NN * DIN;      // [192,256]
    unsigned short* W1lT = W1hT + W1N;
    unsigned short* W2hT = W1lT + W1N;                 // [192,192]
    unsigned short* W2lT = W2hT + W2N;
    unsigned short* WfhT = W2lT + W2N;                 // [64,192]
    unsigned short* WflT = WfhT + WFN;

    const int edge_grid = (NE + 255) / 256;
    const int gemm_grid = (NN + 127) / 128;
    const int gat_grid  = (NN + 1) / 2;
    const int dots_grid = (NN + 3) / 4;
    const int bns_grid  = (NN + 127) / 128;
    const int bna_grid  = (NN * DD / 4 + 255) / 256;
    const int wsp_grid  = (W1N + W2N + WFN + 255) / 256;

    // ---- one memset: DEG + all four BN stat vectors ----
    hipMemsetAsync(DEG, 0, (size_t)NN * 4 + 4 * DD * 4, stream);

    // ---- CSR build (once) ----
    hist_kernel<<<edge_grid, 256, 0, stream>>>(dst, DEG, NE);
    blocksum_kernel<<<NB, 256, 0, stream>>>(DEG, BSUM);
    scan_bsums<<<1, 256, 0, stream>>>(BSUM, BOFF, ROWPTR);
    expand_kernel<<<NB, 256, 0, stream>>>(DEG, BOFF, ROWPTR, CURSOR);
    scatter_kernel<<<edge_grid, 256, 0, stream>>>(src, dst, CURSOR, CSRS, CSRD, NE);

    // ---- weight + input splits ----
    split_x<<<(NN * DIN / 4 + 255) / 256, 256, 0, stream>>>(x, Xh, Xl, NN * DIN);
    wsplit_all<<<wsp_grid, 256, 0, stream>>>(W1, W2, Wf, W1hT, W1lT, W2hT, W2lT, WfhT, WflT);

    // ================= layer 1 =================
    mfma_gemm<DIN, DD, false><<<gemm_grid, 256, 0, stream>>>(
        Xh, Xl, W1hT, W1lT, nullptr, nullptr, Abf, NN);
    attn_dots<<<dots_grid, 256, 0, stream>>>(Abf, as1, ad1, AS, AD);
    edge_w<<<edge_grid, 256, 0, stream>>>(CSRS, CSRD, AS, AD, EW, NE);
    gat_gather<<<gat_grid, 256, 0, stream>>>(Abf, EW, ROWPTR, CSRS, CB1);
    bn_stats<<<bns_grid, 192, 0, stream>>>(CB1, b1, S1a, S2a, NN);
    bn_apply_split<<<bna_grid, 256, 0, stream>>>(CB1, b1, S1a, S2a, g1, be1, Hh, Hl, NN * DD);

    // ================= layer 2 =================
    mfma_gemm<DD, DD, false><<<gemm_grid, 256, 0, stream>>>(
        Hh, Hl, W2hT, W2lT, nullptr, nullptr, Abf, NN);
    attn_dots<<<dots_grid, 256, 0, stream>>>(Abf, as2, ad2, AS, AD);
    edge_w<<<edge_grid, 256, 0, stream>>>(CSRS, CSRD, AS, AD, EW, NE);
    gat_gather<<<gat_grid, 256, 0, stream>>>(Abf, EW, ROWPTR, CSRS, CB2);
    bn_stats<<<bns_grid, 192, 0, stream>>>(CB2, b2, S1b, S2b, NN);
    bn_apply_sum2<<<bna_grid, 256, 0, stream>>>(CB1, b1, S1a, S2a, g1, be1,
                                                CB2, b2, S1b, S2b, g2, be2,
                                                Sh, Sl, NN * DD);

    // ================= final: out = (bn1(h1) + bn2(h2)) @ Wf + bf =================
    mfma_gemm<DD, DF, true><<<gemm_grid, 256, 0, stream>>>(
        Sh, Sl, WfhT, WflT, bf, out, nullptr, NN);
}

// Round 8
// 536.585 us; speedup vs baseline: 1.5047x; 1.0146x over previous
//
#include <hip/hip_runtime.h>

#define NN 50000
#define NE 800000
#define DIN 256
#define NH 3
#define HC 64
#define DD 192
#define DF 64
#define NB 196   // (NN + 255) / 256

typedef __attribute__((ext_vector_type(8))) short s8bf;   // 8 bf16 bit-patterns
typedef __attribute__((ext_vector_type(4))) float f32x4;

// ---- fp32 -> bf16 helpers ----
__device__ __forceinline__ unsigned short f2bf(float f) {
    unsigned u = __float_as_uint(f);
    unsigned r = u + 0x7fffu + ((u >> 16) & 1u);   // round-to-nearest-even
    return (unsigned short)(r >> 16);
}
__device__ __forceinline__ float bf2f(unsigned short h) {
    return __uint_as_float(((unsigned)h) << 16);
}
__device__ __forceinline__ void split2(float f, unsigned short& h, unsigned short& l) {
    h = f2bf(f);
    l = f2bf(f - bf2f(h));
}

// ---- split X [n*K] fp32 -> Xh, Xl bf16 ----
__global__ __launch_bounds__(256)
void split_x(const float* __restrict__ X, unsigned short* __restrict__ Xh,
             unsigned short* __restrict__ Xl, int total) {
    int i = (blockIdx.x * 256 + threadIdx.x) * 4;
    if (i >= total) return;
    float4 v = *(const float4*)(X + i);
    ushort4 h, l;
    split2(v.x, h.x, l.x); split2(v.y, h.y, l.y);
    split2(v.z, h.z, l.z); split2(v.w, h.w, l.w);
    *(ushort4*)(Xh + i) = h;
    *(ushort4*)(Xl + i) = l;
}

// ---- split + transpose all three weights in one dispatch ----
#define W1N (DIN * DD)           // 49152
#define W2N (DD * DD)            // 36864
#define WFN (DD * DF)            // 12288
__global__ __launch_bounds__(256)
void wsplit_all(const float* __restrict__ W1, const float* __restrict__ W2,
                const float* __restrict__ Wf,
                unsigned short* __restrict__ W1hT, unsigned short* __restrict__ W1lT,
                unsigned short* __restrict__ W2hT, unsigned short* __restrict__ W2lT,
                unsigned short* __restrict__ WfhT, unsigned short* __restrict__ WflT) {
    int idx = blockIdx.x * 256 + threadIdx.x;
    const float* W; unsigned short *Wh, *Wl; int K, D, base;
    if (idx < W1N)              { W = W1; Wh = W1hT; Wl = W1lT; K = DIN; D = DD; base = idx; }
    else if (idx < W1N + W2N)   { W = W2; Wh = W2hT; Wl = W2lT; K = DD;  D = DD; base = idx - W1N; }
    else if (idx < W1N + W2N + WFN) { W = Wf; Wh = WfhT; Wl = WflT; K = DD; D = DF; base = idx - W1N - W2N; }
    else return;
    int k = base / D, d = base - k * D;
    unsigned short h, l;
    split2(W[base], h, l);
    Wh[d * K + k] = h;
    Wl[d * K + k] = l;
}

// ---- split-bf16 MFMA GEMM: block = 128 rows x DOUT; wave = 128 rows x DOUT/4 ----
template<int K, int DOUT, bool OUTF32>
__global__ __launch_bounds__(256)
void mfma_gemm(const unsigned short* __restrict__ Ah, const unsigned short* __restrict__ Al,
               const unsigned short* __restrict__ BhT, const unsigned short* __restrict__ BlT,
               const float* __restrict__ obias, float* __restrict__ Yf,
               unsigned short* __restrict__ Yb, int n) {
    constexpr int NT = DOUT / 64;            // 16-col tiles per wave
    const int wave = threadIdx.x >> 6, lane = threadIdx.x & 63;
    const int r = lane & 15, kg = lane >> 4;
    const int row0 = blockIdx.x * 128;
    const int col0 = wave * (DOUT / 4);

    f32x4 acc[8][NT] = {};

    int aoff[8];
#pragma unroll
    for (int g = 0; g < 8; ++g)
        aoff[g] = min(row0 + g * 16 + r, n - 1) * K + kg * 8;
    int boff[NT];
#pragma unroll
    for (int t = 0; t < NT; ++t)
        boff[t] = (col0 + t * 16 + r) * K + kg * 8;

    for (int k0 = 0; k0 < K; k0 += 32) {
        s8bf ah[8], al[8], bh[NT], bl[NT];
#pragma unroll
        for (int t = 0; t < NT; ++t) {
            bh[t] = *(const s8bf*)(BhT + boff[t] + k0);
            bl[t] = *(const s8bf*)(BlT + boff[t] + k0);
        }
#pragma unroll
        for (int g = 0; g < 8; ++g) {
            ah[g] = *(const s8bf*)(Ah + aoff[g] + k0);
            al[g] = *(const s8bf*)(Al + aoff[g] + k0);
        }
#pragma unroll
        for (int g = 0; g < 8; ++g)
#pragma unroll
            for (int t = 0; t < NT; ++t) {
                acc[g][t] = __builtin_amdgcn_mfma_f32_16x16x32_bf16(ah[g], bh[t], acc[g][t], 0, 0, 0);
                acc[g][t] = __builtin_amdgcn_mfma_f32_16x16x32_bf16(ah[g], bl[t], acc[g][t], 0, 0, 0);
                acc[g][t] = __builtin_amdgcn_mfma_f32_16x16x32_bf16(al[g], bh[t], acc[g][t], 0, 0, 0);
            }
    }

    // C layout: col = lane&15 (within tile), row = (lane>>4)*4 + reg
#pragma unroll
    for (int t = 0; t < NT; ++t) {
        int col = col0 + t * 16 + r;
        float b = OUTF32 ? obias[col] : 0.f;
#pragma unroll
        for (int g = 0; g < 8; ++g) {
#pragma unroll
            for (int rr = 0; rr < 4; ++rr) {
                int row = row0 + g * 16 + kg * 4 + rr;
                if (row < n) {
                    if constexpr (OUTF32)
                        Yf[(size_t)row * DOUT + col] = acc[g][t][rr] + b;
                    else
                        Yb[(size_t)row * DOUT + col] = f2bf(acc[g][t][rr]);
                }
            }
        }
    }
}

// ---- per-node attention dots: one wave per node, 4 nodes/block ----
__global__ __launch_bounds__(256)
void attn_dots(const unsigned short* __restrict__ xf,
               const float* __restrict__ att_s, const float* __restrict__ att_d,
               float* __restrict__ as_, float* __restrict__ ad_) {
    int wid = blockIdx.x * 4 + (threadIdx.x >> 6);
    if (wid >= NN) return;
    int lane = threadIdx.x & 63;
    const unsigned short* xp = xf + (size_t)wid * DD;
    float v0 = bf2f(xp[lane]), v1 = bf2f(xp[64 + lane]), v2 = bf2f(xp[128 + lane]);
    float s0 = v0 * att_s[lane], s1 = v1 * att_s[64 + lane], s2 = v2 * att_s[128 + lane];
    float d0 = v0 * att_d[lane], d1 = v1 * att_d[64 + lane], d2 = v2 * att_d[128 + lane];
#pragma unroll
    for (int off = 32; off; off >>= 1) {
        s0 += __shfl_down(s0, off); s1 += __shfl_down(s1, off); s2 += __shfl_down(s2, off);
        d0 += __shfl_down(d0, off); d1 += __shfl_down(d1, off); d2 += __shfl_down(d2, off);
    }
    if (lane == 0) {
        as_[wid * NH + 0] = s0; as_[wid * NH + 1] = s1; as_[wid * NH + 2] = s2;
        ad_[wid * NH + 0] = d0; ad_[wid * NH + 1] = d1; ad_[wid * NH + 2] = d2;
    }
}

// ============ CSR build ============
__global__ void hist_kernel(const int* __restrict__ dst, int* __restrict__ deg, int ne) {
    int e = blockIdx.x * blockDim.x + threadIdx.x;
    if (e < ne) atomicAdd(&deg[dst[e]], 1);
}

__global__ __launch_bounds__(256)
void blocksum_kernel(const int* __restrict__ deg, int* __restrict__ bsum) {
    int i = blockIdx.x * 256 + threadIdx.x;
    int v = (i < NN) ? deg[i] : 0;
#pragma unroll
    for (int off = 32; off; off >>= 1) v += __shfl_down(v, off);
    __shared__ int ws[4];
    if ((threadIdx.x & 63) == 0) ws[threadIdx.x >> 6] = v;
    __syncthreads();
    if (threadIdx.x == 0) bsum[blockIdx.x] = ws[0] + ws[1] + ws[2] + ws[3];
}

__global__ __launch_bounds__(256)
void scan_bsums(const int* __restrict__ bsum, int* __restrict__ boff,
                int* __restrict__ rowptr) {
    __shared__ int s[256];
    int t = threadIdx.x;
    int v = (t < NB) ? bsum[t] : 0;
    s[t] = v;
    __syncthreads();
    for (int off = 1; off < 256; off <<= 1) {
        int u = (t >= off) ? s[t - off] : 0;
        __syncthreads();
        s[t] += u;
        __syncthreads();
    }
    if (t < NB) boff[t] = s[t] - v;
    if (t == 255) rowptr[NN] = s[255];
}

__global__ __launch_bounds__(256)
void expand_kernel(const int* __restrict__ deg, const int* __restrict__ boff,
                   int* __restrict__ rowptr, int* __restrict__ cursor) {
    __shared__ int s[256];
    int t = threadIdx.x;
    int i = blockIdx.x * 256 + t;
    int v = (i < NN) ? deg[i] : 0;
    s[t] = v;
    __syncthreads();
    for (int off = 1; off < 256; off <<= 1) {
        int u = (t >= off) ? s[t - off] : 0;
        __syncthreads();
        s[t] += u;
        __syncthreads();
    }
    if (i < NN) {
        int excl = s[t] - v + boff[blockIdx.x];
        rowptr[i] = excl;
        cursor[i] = excl;
    }
}

__global__ void scatter_kernel(const int* __restrict__ src, const int* __restrict__ dst,
                               int* __restrict__ cursor, int* __restrict__ csr_src, int ne) {
    int e = blockIdx.x * blockDim.x + threadIdx.x;
    if (e >= ne) return;
    int d = dst[e];
    int pos = atomicAdd(&cursor[d], 1);
    csr_src[pos] = src[e];
}

// ============ GAT gather: batched edge prefetch + readlane broadcast ============
// one wave per node; lane owns channels {lane, lane+64, lane+128}; bf16 feats.
// Batch phase (lane-parallel): load csr_src + compute exp-weights for 64 edges.
// Serial phase: broadcast s,w via v_readlane (no memory), 3 feature gathers/edge.
__global__ __launch_bounds__(256)
void gat_gather(const unsigned short* __restrict__ xf,
                const float* __restrict__ as_, const float* __restrict__ ad_,
                const int* __restrict__ rowptr, const int* __restrict__ csr_src,
                float* __restrict__ outp) {
    int d = blockIdx.x * 4 + (threadIdx.x >> 6);
    if (d >= NN) return;
    const int lane = threadIdx.x & 63;
    const int beg = rowptr[d], end = rowptr[d + 1];
    const float ad0 = ad_[d * NH + 0], ad1 = ad_[d * NH + 1], ad2 = ad_[d * NH + 2];

    float a0 = 0.f, a1 = 0.f, a2 = 0.f;
    float den0 = 0.f, den1 = 0.f, den2 = 0.f;

    for (int base = beg; base < end; base += 64) {
        const int nb = min(64, end - base);
        int sl = 0;
        float w0 = 0.f, w1 = 0.f, w2 = 0.f;
        if (lane < nb) {
            sl = csr_src[base + lane];
            float e0 = as_[sl * NH + 0] + ad0;
            float e1 = as_[sl * NH + 1] + ad1;
            float e2 = as_[sl * NH + 2] + ad2;
            e0 = e0 > 0.f ? e0 : 0.2f * e0;
            e1 = e1 > 0.f ? e1 : 0.2f * e1;
            e2 = e2 > 0.f ? e2 : 0.2f * e2;
            w0 = __expf(e0); w1 = __expf(e1); w2 = __expf(e2);
        }
        // den via butterfly reduce (DS pipe) -- off the serial VALU path
        float r0 = w0, r1 = w1, r2 = w2;
#pragma unroll
        for (int off = 1; off < 64; off <<= 1) {
            r0 += __shfl_xor(r0, off);
            r1 += __shfl_xor(r1, off);
            r2 += __shfl_xor(r2, off);
        }
        den0 += r0; den1 += r1; den2 += r2;

        for (int j = 0; j < nb; ++j) {
            int s = __builtin_amdgcn_readlane(sl, j);
            float u0 = __int_as_float(__builtin_amdgcn_readlane(__float_as_int(w0), j));
            float u1 = __int_as_float(__builtin_amdgcn_readlane(__float_as_int(w1), j));
            float u2 = __int_as_float(__builtin_amdgcn_readlane(__float_as_int(w2), j));
            const unsigned short* xp = xf + (size_t)s * DD;
            a0 = fmaf(bf2f(xp[lane]),       u0, a0);
            a1 = fmaf(bf2f(xp[64 + lane]),  u1, a1);
            a2 = fmaf(bf2f(xp[128 + lane]), u2, a2);
        }
    }
    size_t o = (size_t)d * DD + lane;
    outp[o]       = a0 / (den0 + 1e-16f);
    outp[o + 64]  = a1 / (den1 + 1e-16f);
    outp[o + 128] = a2 / (den2 + 1e-16f);
}

// ---- BN pass 1: per-feature sum / sumsq of relu(h + bias) ----
__global__ __launch_bounds__(192)
void bn_stats(const float* __restrict__ hbuf, const float* __restrict__ bias,
              float* __restrict__ s1, float* __restrict__ s2, int n) {
    int j = threadIdx.x;
    float b = bias[j];
    int r0 = blockIdx.x * 128;
    int r1 = min(r0 + 128, n);
    float a = 0.f, q = 0.f;
    for (int r = r0; r < r1; ++r) {
        float v = hbuf[(size_t)r * DD + j] + b;
        v = fmaxf(v, 0.f);
        a += v; q += v * v;
    }
    atomicAdd(&s1[j], a);
    atomicAdd(&s2[j], q);
}

// ---- BN apply (finalize inline): y = bn(relu(in+bias)) -> bf16 hi/lo ----
__global__ __launch_bounds__(256)
void bn_apply_split(const float* __restrict__ in, const float* __restrict__ bias,
                    const float* __restrict__ S1, const float* __restrict__ S2,
                    const float* __restrict__ g, const float* __restrict__ beta,
                    unsigned short* __restrict__ oh, unsigned short* __restrict__ ol, int total) {
    int i = (blockIdx.x * 256 + threadIdx.x) * 4;
    if (i >= total) return;
    int j = i % DD;
    const float invn = 1.0f / NN;
    float4 v = *(const float4*)(in + i);
    float vv[4] = {v.x, v.y, v.z, v.w};
    ushort4 h, l;
    unsigned short* hp = (unsigned short*)&h;
    unsigned short* lp = (unsigned short*)&l;
#pragma unroll
    for (int q = 0; q < 4; ++q) {
        float mu = S1[j + q] * invn;
        float var = S2[j + q] * invn - mu * mu;
        float sc = g[j + q] * rsqrtf(var + 1e-5f);
        float sh = beta[j + q] - mu * sc;
        float y = fmaxf(vv[q] + bias[j + q], 0.f) * sc + sh;
        split2(y, hp[q], lp[q]);
    }
    *(ushort4*)(oh + i) = h;
    *(ushort4*)(ol + i) = l;
}

// ---- BN apply-sum (finalize inline): y = bn1(relu(C1+b1)) + bn2(relu(C2+b2)) ----
__global__ __launch_bounds__(256)
void bn_apply_sum2(const float* __restrict__ C1, const float* __restrict__ b1,
                   const float* __restrict__ S1a, const float* __restrict__ S2a,
                   const float* __restrict__ g1, const float* __restrict__ be1,
                   const float* __restrict__ C2, const float* __restrict__ b2,
                   const float* __restrict__ S1b, const float* __restrict__ S2b,
                   const float* __restrict__ g2, const float* __restrict__ be2,
                   unsigned short* __restrict__ oh, unsigned short* __restrict__ ol, int total) {
    int i = (blockIdx.x * 256 + threadIdx.x) * 4;
    if (i >= total) return;
    int j = i % DD;
    const float invn = 1.0f / NN;
    float4 v1 = *(const float4*)(C1 + i);
    float4 v2 = *(const float4*)(C2 + i);
    float a1[4] = {v1.x, v1.y, v1.z, v1.w};
    float a2[4] = {v2.x, v2.y, v2.z, v2.w};
    ushort4 h, l;
    unsigned short* hp = (unsigned short*)&h;
    unsigned short* lp = (unsigned short*)&l;
#pragma unroll
    for (int q = 0; q < 4; ++q) {
        float mu1 = S1a[j + q] * invn;
        float var1 = S2a[j + q] * invn - mu1 * mu1;
        float sc1 = g1[j + q] * rsqrtf(var1 + 1e-5f);
        float sh1 = be1[j + q] - mu1 * sc1;
        float mu2 = S1b[j + q] * invn;
        float var2 = S2b[j + q] * invn - mu2 * mu2;
        float sc2 = g2[j + q] * rsqrtf(var2 + 1e-5f);
        float sh2 = be2[j + q] - mu2 * sc2;
        float y = fmaxf(a1[q] + b1[j + q], 0.f) * sc1 + sh1
                + fmaxf(a2[q] + b2[j + q], 0.f) * sc2 + sh2;
        split2(y, hp[q], lp[q]);
    }
    *(ushort4*)(oh + i) = h;
    *(ushort4*)(ol + i) = l;
}

extern "C" void kernel_launch(void* const* d_in, const int* in_sizes, int n_in,
                              void* d_out, int out_size, void* d_ws, size_t ws_size,
                              hipStream_t stream) {
    const float* x   = (const float*)d_in[0];
    const float* W1  = (const float*)d_in[1];
    const float* as1 = (const float*)d_in[2];
    const float* ad1 = (const float*)d_in[3];
    const float* b1  = (const float*)d_in[4];
    const float* g1  = (const float*)d_in[5];
    const float* be1 = (const float*)d_in[6];
    const float* W2  = (const float*)d_in[7];
    const float* as2 = (const float*)d_in[8];
    const float* ad2 = (const float*)d_in[9];
    const float* b2  = (const float*)d_in[10];
    const float* g2  = (const float*)d_in[11];
    const float* be2 = (const float*)d_in[12];
    const float* Wf  = (const float*)d_in[13];
    const float* bf  = (const float*)d_in[14];
    const int*   ei  = (const int*)d_in[15];
    const int* src = ei;
    const int* dst = ei + NE;
    float* out = (float*)d_out;

    float* ws = (float*)d_ws;
    float* CB1 = ws;                          // [N,192]
    float* CB2 = CB1 + (size_t)NN * DD;       // [N,192]
    float* AS  = CB2 + (size_t)NN * DD;       // [N,3]
    float* AD  = AS  + (size_t)NN * NH;       // [N,3]
    int* DEG   = (int*)(AD + (size_t)NN * NH);// [N]   (zeroed together with stats)
    float* S1a = (float*)(DEG + NN);          // [192] x4 stats, contiguous after DEG
    float* S2a = S1a + DD;
    float* S1b = S2a + DD;
    float* S2b = S1b + DD;
    int* ROWPTR = (int*)(S2b + DD);           // [N+1]
    int* CURSOR = ROWPTR + NN + 1;            // [N]
    int* BSUM   = CURSOR + NN;                // [NB]
    int* BOFF   = BSUM + NB;                  // [NB]
    int* CSRS   = BOFF + NB;                  // [E]
    unsigned short* R    = (unsigned short*)(CSRS + NE);
    unsigned short* Abf  = R;                          // [N,192] bf16 features
    unsigned short* Xh   = Abf + (size_t)NN * DD;      // [N,256] -> later Hh/Sh
    unsigned short* Xl   = Xh + (size_t)NN * DIN;      // [N,256] -> later Hl/Sl
    unsigned short* Hh   = Xh;
    unsigned short* Hl   = Xl;
    unsigned short* Sh   = Xh;
    unsigned short* Sl   = Xl;
    unsigned short* W1hT = Xl + (size_t)NN * DIN;      // [192,256]
    unsigned short* W1lT = W1hT + W1N;
    unsigned short* W2hT = W1lT + W1N;                 // [192,192]
    unsigned short* W2lT = W2hT + W2N;
    unsigned short* WfhT = W2lT + W2N;                 // [64,192]
    unsigned short* WflT = WfhT + WFN;

    const int edge_grid = (NE + 255) / 256;
    const int gemm_grid = (NN + 127) / 128;
    const int gat_grid  = (NN + 3) / 4;
    const int dots_grid = (NN + 3) / 4;
    const int bns_grid  = (NN + 127) / 128;
    const int bna_grid  = (NN * DD / 4 + 255) / 256;
    const int wsp_grid  = (W1N + W2N + WFN + 255) / 256;

    // ---- one memset: DEG + all four BN stat vectors ----
    hipMemsetAsync(DEG, 0, (size_t)NN * 4 + 4 * DD * 4, stream);

    // ---- CSR build (once) ----
    hist_kernel<<<edge_grid, 256, 0, stream>>>(dst, DEG, NE);
    blocksum_kernel<<<NB, 256, 0, stream>>>(DEG, BSUM);
    scan_bsums<<<1, 256, 0, stream>>>(BSUM, BOFF, ROWPTR);
    expand_kernel<<<NB, 256, 0, stream>>>(DEG, BOFF, ROWPTR, CURSOR);
    scatter_kernel<<<edge_grid, 256, 0, stream>>>(src, dst, CURSOR, CSRS, NE);

    // ---- weight + input splits ----
    split_x<<<(NN * DIN / 4 + 255) / 256, 256, 0, stream>>>(x, Xh, Xl, NN * DIN);
    wsplit_all<<<wsp_grid, 256, 0, stream>>>(W1, W2, Wf, W1hT, W1lT, W2hT, W2lT, WfhT, WflT);

    // ================= layer 1 =================
    mfma_gemm<DIN, DD, false><<<gemm_grid, 256, 0, stream>>>(
        Xh, Xl, W1hT, W1lT, nullptr, nullptr, Abf, NN);
    attn_dots<<<dots_grid, 256, 0, stream>>>(Abf, as1, ad1, AS, AD);
    gat_gather<<<gat_grid, 256, 0, stream>>>(Abf, AS, AD, ROWPTR, CSRS, CB1);
    bn_stats<<<bns_grid, 192, 0, stream>>>(CB1, b1, S1a, S2a, NN);
    bn_apply_split<<<bna_grid, 256, 0, stream>>>(CB1, b1, S1a, S2a, g1, be1, Hh, Hl, NN * DD);

    // ================= layer 2 =================
    mfma_gemm<DD, DD, false><<<gemm_grid, 256, 0, stream>>>(
        Hh, Hl, W2hT, W2lT, nullptr, nullptr, Abf, NN);
    attn_dots<<<dots_grid, 256, 0, stream>>>(Abf, as2, ad2, AS, AD);
    gat_gather<<<gat_grid, 256, 0, stream>>>(Abf, AS, AD, ROWPTR, CSRS, CB2);
    bn_stats<<<bns_grid, 192, 0, stream>>>(CB2, b2, S1b, S2b, NN);
    bn_apply_sum2<<<bna_grid, 256, 0, stream>>>(CB1, b1, S1a, S2a, g1, be1,
                                                CB2, b2, S1b, S2b, g2, be2,
                                                Sh, Sl, NN * DD);

    // ================= final: out = (bn1(h1) + bn2(h2)) @ Wf + bf =================
    mfma_gemm<DD, DF, true><<<gemm_grid, 256, 0, stream>>>(
        Sh, Sl, WfhT, WflT, bf, out, nullptr, NN);
}

// Round 9
// 458.888 us; speedup vs baseline: 1.7594x; 1.1693x over previous
//
#include <hip/hip_runtime.h>

#define NN 50000
#define NE 800000
#define DIN 256
#define NH 3
#define HC 64
#define DD 192
#define DF 64
#define NB 196   // (NN + 255) / 256

typedef __attribute__((ext_vector_type(8))) short s8bf;            // 8 bf16 bit-patterns
typedef __attribute__((ext_vector_type(8))) unsigned short u16x8;
typedef __attribute__((ext_vector_type(4))) float f32x4;

// ---- fp32 -> bf16 helpers ----
__device__ __forceinline__ unsigned short f2bf(float f) {
    unsigned u = __float_as_uint(f);
    unsigned r = u + 0x7fffu + ((u >> 16) & 1u);   // round-to-nearest-even
    return (unsigned short)(r >> 16);
}
__device__ __forceinline__ float bf2f(unsigned short h) {
    return __uint_as_float(((unsigned)h) << 16);
}
__device__ __forceinline__ void split2(float f, unsigned short& h, unsigned short& l) {
    h = f2bf(f);
    l = f2bf(f - bf2f(h));
}

// ---- split + transpose all three weights in one dispatch ----
#define W1N (DIN * DD)           // 49152
#define W2N (DD * DD)            // 36864
#define WFN (DD * DF)            // 12288
__global__ __launch_bounds__(256)
void wsplit_all(const float* __restrict__ W1, const float* __restrict__ W2,
                const float* __restrict__ Wf,
                unsigned short* __restrict__ W1hT, unsigned short* __restrict__ W1lT,
                unsigned short* __restrict__ W2hT, unsigned short* __restrict__ W2lT,
                unsigned short* __restrict__ WfhT, unsigned short* __restrict__ WflT) {
    int idx = blockIdx.x * 256 + threadIdx.x;
    const float* W; unsigned short *Wh, *Wl; int K, D, base;
    if (idx < W1N)              { W = W1; Wh = W1hT; Wl = W1lT; K = DIN; D = DD; base = idx; }
    else if (idx < W1N + W2N)   { W = W2; Wh = W2hT; Wl = W2lT; K = DD;  D = DD; base = idx - W1N; }
    else if (idx < W1N + W2N + WFN) { W = Wf; Wh = WfhT; Wl = WflT; K = DD; D = DF; base = idx - W1N - W2N; }
    else return;
    int k = base / D, d = base - k * D;
    unsigned short h, l;
    split2(W[base], h, l);
    Wh[d * K + k] = h;
    Wl[d * K + k] = l;
}

// ---- BN finalize: scale/shift from accumulated stats ----
__global__ void bn_fin(const float* __restrict__ s1, const float* __restrict__ s2,
                       const float* __restrict__ g, const float* __restrict__ beta,
                       float* __restrict__ scale, float* __restrict__ shift) {
    int j = threadIdx.x;
    const float invn = 1.0f / NN;
    float mu = s1[j] * invn;
    float var = s2[j] * invn - mu * mu;
    float sc = g[j] * rsqrtf(var + 1e-5f);
    scale[j] = sc;
    shift[j] = beta[j] - mu * sc;
}

// ---- LDS-staged split-bf16 MFMA GEMM; A built on the fly ----
// MODE 0: A = A1 (fp32) split to hi/lo                    -> Yb bf16
// MODE 1: A = relu(A1 + bb1)*sc1 + sh1                    -> Yb bf16
// MODE 2: A = bn1(A1) + bn2(A2)                           -> Yf fp32 + obias
// block = 64 rows x DOUT; 4 waves; LDS layout AH/AL[K/8][64][8] (conflict-free b128)
template<int K, int DOUT, int MODE>
__global__ __launch_bounds__(256)
void mfma_gemm(const float* __restrict__ A1, const float* __restrict__ A2,
               const float* __restrict__ bb1, const float* __restrict__ sc1, const float* __restrict__ sh1,
               const float* __restrict__ bb2, const float* __restrict__ sc2, const float* __restrict__ sh2,
               const unsigned short* __restrict__ BhT, const unsigned short* __restrict__ BlT,
               const float* __restrict__ obias, float* __restrict__ Yf,
               unsigned short* __restrict__ Yb, int n) {
    constexpr int KB = K / 8;
    constexpr int NT = DOUT / 64;            // 16-col tiles per wave (192->3, 64->1)
    __shared__ unsigned short AH[KB][64][8];
    __shared__ unsigned short AL[KB][64][8];

    const int tid = threadIdx.x;
    const int wave = tid >> 6, lane = tid & 63;
    const int r = lane & 15, kg = lane >> 4;
    const int row0 = blockIdx.x * 64;
    const int col0 = wave * (DOUT / 4);

    // ---- stage A panel: fp32 -> (BN) -> hi/lo bf16 in LDS ----
    for (int idx = tid; idx < 64 * KB; idx += 256) {
        int rr = idx / KB, kb = idx - rr * KB;
        int grow = min(row0 + rr, n - 1);
        int j = kb * 8;
        const float* ap = A1 + (size_t)grow * K + j;
        float v[8];
        *(float4*)&v[0] = *(const float4*)ap;
        *(float4*)&v[4] = *(const float4*)(ap + 4);
        if constexpr (MODE >= 1) {
#pragma unroll
            for (int q = 0; q < 8; ++q)
                v[q] = fmaxf(v[q] + bb1[j + q], 0.f) * sc1[j + q] + sh1[j + q];
        }
        if constexpr (MODE == 2) {
            const float* ap2 = A2 + (size_t)grow * K + j;
            float u[8];
            *(float4*)&u[0] = *(const float4*)ap2;
            *(float4*)&u[4] = *(const float4*)(ap2 + 4);
#pragma unroll
            for (int q = 0; q < 8; ++q)
                v[q] += fmaxf(u[q] + bb2[j + q], 0.f) * sc2[j + q] + sh2[j + q];
        }
        u16x8 hv, lv;
#pragma unroll
        for (int q = 0; q < 8; ++q) {
            unsigned short h, l;
            split2(v[q], h, l);
            hv[q] = h; lv[q] = l;
        }
        *(u16x8*)&AH[kb][rr][0] = hv;
        *(u16x8*)&AL[kb][rr][0] = lv;
    }
    __syncthreads();

    // ---- K loop: B pair from global (L2-hot), A fragments from LDS ----
    int boff[NT];
#pragma unroll
    for (int t = 0; t < NT; ++t)
        boff[t] = (col0 + t * 16 + r) * K + kg * 8;

    f32x4 acc[4][NT] = {};
    for (int k0 = 0; k0 < K; k0 += 32) {
        s8bf bh[NT], bl[NT];
#pragma unroll
        for (int t = 0; t < NT; ++t) {
            bh[t] = *(const s8bf*)(BhT + boff[t] + k0);
            bl[t] = *(const s8bf*)(BlT + boff[t] + k0);
        }
        const int kb = k0 / 8 + kg;
        s8bf ah[4], al[4];
#pragma unroll
        for (int g = 0; g < 4; ++g) {
            ah[g] = *(const s8bf*)&AH[kb][g * 16 + r][0];
            al[g] = *(const s8bf*)&AL[kb][g * 16 + r][0];
        }
#pragma unroll
        for (int g = 0; g < 4; ++g)
#pragma unroll
            for (int t = 0; t < NT; ++t) {
                acc[g][t] = __builtin_amdgcn_mfma_f32_16x16x32_bf16(ah[g], bh[t], acc[g][t], 0, 0, 0);
                acc[g][t] = __builtin_amdgcn_mfma_f32_16x16x32_bf16(ah[g], bl[t], acc[g][t], 0, 0, 0);
                acc[g][t] = __builtin_amdgcn_mfma_f32_16x16x32_bf16(al[g], bh[t], acc[g][t], 0, 0, 0);
            }
    }

    // C layout: col = lane&15 (within tile), row = (lane>>4)*4 + reg
#pragma unroll
    for (int t = 0; t < NT; ++t) {
        int col = col0 + t * 16 + r;
        float b = (MODE == 2) ? obias[col] : 0.f;
#pragma unroll
        for (int g = 0; g < 4; ++g) {
#pragma unroll
            for (int rr = 0; rr < 4; ++rr) {
                int row = row0 + g * 16 + kg * 4 + rr;
                if (row < n) {
                    if constexpr (MODE == 2)
                        Yf[(size_t)row * DOUT + col] = acc[g][t][rr] + b;
                    else
                        Yb[(size_t)row * DOUT + col] = f2bf(acc[g][t][rr]);
                }
            }
        }
    }
}

// ---- per-node attention dots: one wave per node, 4 nodes/block; float4 out ----
__global__ __launch_bounds__(256)
void attn_dots(const unsigned short* __restrict__ xf,
               const float* __restrict__ att_s, const float* __restrict__ att_d,
               float4* __restrict__ as4, float4* __restrict__ ad4) {
    int wid = blockIdx.x * 4 + (threadIdx.x >> 6);
    if (wid >= NN) return;
    int lane = threadIdx.x & 63;
    const unsigned short* xp = xf + (size_t)wid * DD;
    float v0 = bf2f(xp[lane]), v1 = bf2f(xp[64 + lane]), v2 = bf2f(xp[128 + lane]);
    float s0 = v0 * att_s[lane], s1 = v1 * att_s[64 + lane], s2 = v2 * att_s[128 + lane];
    float d0 = v0 * att_d[lane], d1 = v1 * att_d[64 + lane], d2 = v2 * att_d[128 + lane];
#pragma unroll
    for (int off = 32; off; off >>= 1) {
        s0 += __shfl_down(s0, off); s1 += __shfl_down(s1, off); s2 += __shfl_down(s2, off);
        d0 += __shfl_down(d0, off); d1 += __shfl_down(d1, off); d2 += __shfl_down(d2, off);
    }
    if (lane == 0) {
        as4[wid] = make_float4(s0, s1, s2, 0.f);
        ad4[wid] = make_float4(d0, d1, d2, 0.f);
    }
}

// ============ CSR build ============
__global__ void hist_kernel(const int* __restrict__ dst, int* __restrict__ deg, int ne) {
    int e = blockIdx.x * blockDim.x + threadIdx.x;
    if (e < ne) atomicAdd(&deg[dst[e]], 1);
}

__global__ __launch_bounds__(256)
void blocksum_kernel(const int* __restrict__ deg, int* __restrict__ bsum) {
    int i = blockIdx.x * 256 + threadIdx.x;
    int v = (i < NN) ? deg[i] : 0;
#pragma unroll
    for (int off = 32; off; off >>= 1) v += __shfl_down(v, off);
    __shared__ int ws[4];
    if ((threadIdx.x & 63) == 0) ws[threadIdx.x >> 6] = v;
    __syncthreads();
    if (threadIdx.x == 0) bsum[blockIdx.x] = ws[0] + ws[1] + ws[2] + ws[3];
}

__global__ __launch_bounds__(256)
void scan_bsums(const int* __restrict__ bsum, int* __restrict__ boff,
                int* __restrict__ rowptr) {
    __shared__ int s[256];
    int t = threadIdx.x;
    int v = (t < NB) ? bsum[t] : 0;
    s[t] = v;
    __syncthreads();
    for (int off = 1; off < 256; off <<= 1) {
        int u = (t >= off) ? s[t - off] : 0;
        __syncthreads();
        s[t] += u;
        __syncthreads();
    }
    if (t < NB) boff[t] = s[t] - v;
    if (t == 255) rowptr[NN] = s[255];
}

__global__ __launch_bounds__(256)
void expand_kernel(const int* __restrict__ deg, const int* __restrict__ boff,
                   int* __restrict__ rowptr, int* __restrict__ cursor) {
    __shared__ int s[256];
    int t = threadIdx.x;
    int i = blockIdx.x * 256 + t;
    int v = (i < NN) ? deg[i] : 0;
    s[t] = v;
    __syncthreads();
    for (int off = 1; off < 256; off <<= 1) {
        int u = (t >= off) ? s[t - off] : 0;
        __syncthreads();
        s[t] += u;
        __syncthreads();
    }
    if (i < NN) {
        int excl = s[t] - v + boff[blockIdx.x];
        rowptr[i] = excl;
        cursor[i] = excl;
    }
}

__global__ void scatter_kernel(const int* __restrict__ src, const int* __restrict__ dst,
                               int* __restrict__ cursor, int* __restrict__ csr_src, int ne) {
    int e = blockIdx.x * blockDim.x + threadIdx.x;
    if (e >= ne) return;
    int d = dst[e];
    int pos = atomicAdd(&cursor[d], 1);
    csr_src[pos] = src[e];
}

// ============ GAT gather: batched edge prefetch + readlane broadcast ============
__global__ __launch_bounds__(256)
void gat_gather(const unsigned short* __restrict__ xf,
                const float4* __restrict__ as4, const float4* __restrict__ ad4,
                const int* __restrict__ rowptr, const int* __restrict__ csr_src,
                float* __restrict__ outp) {
    int d = blockIdx.x * 4 + (threadIdx.x >> 6);
    if (d >= NN) return;
    const int lane = threadIdx.x & 63;
    const int beg = rowptr[d], end = rowptr[d + 1];
    const float4 adv = ad4[d];

    float a0 = 0.f, a1 = 0.f, a2 = 0.f;
    float den0 = 0.f, den1 = 0.f, den2 = 0.f;

    for (int base = beg; base < end; base += 64) {
        const int nb = min(64, end - base);
        int sl = 0;
        float w0 = 0.f, w1 = 0.f, w2 = 0.f;
        if (lane < nb) {
            sl = csr_src[base + lane];
            float4 av = as4[sl];               // one 16B gather per lane
            float e0 = av.x + adv.x;
            float e1 = av.y + adv.y;
            float e2 = av.z + adv.z;
            e0 = e0 > 0.f ? e0 : 0.2f * e0;
            e1 = e1 > 0.f ? e1 : 0.2f * e1;
            e2 = e2 > 0.f ? e2 : 0.2f * e2;
            w0 = __expf(e0); w1 = __expf(e1); w2 = __expf(e2);
        }
        float r0 = w0, r1 = w1, r2 = w2;
#pragma unroll
        for (int off = 1; off < 64; off <<= 1) {
            r0 += __shfl_xor(r0, off);
            r1 += __shfl_xor(r1, off);
            r2 += __shfl_xor(r2, off);
        }
        den0 += r0; den1 += r1; den2 += r2;

        for (int j = 0; j < nb; ++j) {
            int s = __builtin_amdgcn_readlane(sl, j);
            float u0 = __int_as_float(__builtin_amdgcn_readlane(__float_as_int(w0), j));
            float u1 = __int_as_float(__builtin_amdgcn_readlane(__float_as_int(w1), j));
            float u2 = __int_as_float(__builtin_amdgcn_readlane(__float_as_int(w2), j));
            const unsigned short* xp = xf + (size_t)s * DD;
            a0 = fmaf(bf2f(xp[lane]),       u0, a0);
            a1 = fmaf(bf2f(xp[64 + lane]),  u1, a1);
            a2 = fmaf(bf2f(xp[128 + lane]), u2, a2);
        }
    }
    size_t o = (size_t)d * DD + lane;
    outp[o]       = a0 / (den0 + 1e-16f);
    outp[o + 64]  = a1 / (den1 + 1e-16f);
    outp[o + 128] = a2 / (den2 + 1e-16f);
}

// ---- BN pass 1: per-feature sum / sumsq of relu(h + bias) ----
__global__ __launch_bounds__(192)
void bn_stats(const float* __restrict__ hbuf, const float* __restrict__ bias,
              float* __restrict__ s1, float* __restrict__ s2, int n) {
    int j = threadIdx.x;
    float b = bias[j];
    int r0 = blockIdx.x * 128;
    int r1 = min(r0 + 128, n);
    float a = 0.f, q = 0.f;
    for (int r = r0; r < r1; ++r) {
        float v = hbuf[(size_t)r * DD + j] + b;
        v = fmaxf(v, 0.f);
        a += v; q += v * v;
    }
    atomicAdd(&s1[j], a);
    atomicAdd(&s2[j], q);
}

extern "C" void kernel_launch(void* const* d_in, const int* in_sizes, int n_in,
                              void* d_out, int out_size, void* d_ws, size_t ws_size,
                              hipStream_t stream) {
    const float* x   = (const float*)d_in[0];
    const float* W1  = (const float*)d_in[1];
    const float* as1 = (const float*)d_in[2];
    const float* ad1 = (const float*)d_in[3];
    const float* b1  = (const float*)d_in[4];
    const float* g1  = (const float*)d_in[5];
    const float* be1 = (const float*)d_in[6];
    const float* W2  = (const float*)d_in[7];
    const float* as2 = (const float*)d_in[8];
    const float* ad2 = (const float*)d_in[9];
    const float* b2  = (const float*)d_in[10];
    const float* g2  = (const float*)d_in[11];
    const float* be2 = (const float*)d_in[12];
    const float* Wf  = (const float*)d_in[13];
    const float* bf  = (const float*)d_in[14];
    const int*   ei  = (const int*)d_in[15];
    const int* src = ei;
    const int* dst = ei + NE;
    float* out = (float*)d_out;

    float* ws = (float*)d_ws;
    float* CB1 = ws;                          // [N,192]
    float* CB2 = CB1 + (size_t)NN * DD;       // [N,192]
    float4* AS4 = (float4*)(CB2 + (size_t)NN * DD);   // [N] float4
    float4* AD4 = AS4 + NN;                   // [N] float4
    int* DEG   = (int*)(AD4 + NN);            // [N]  (zeroed together with stats)
    float* S1a = (float*)(DEG + NN);          // [192] x4 stats
    float* S2a = S1a + DD;
    float* S1b = S2a + DD;
    float* S2b = S1b + DD;
    float* SC1 = S2b + DD;                    // [192] x4 scale/shift
    float* SH1 = SC1 + DD;
    float* SC2 = SH1 + DD;
    float* SH2 = SC2 + DD;
    int* ROWPTR = (int*)(SH2 + DD);           // [N+1]
    int* CURSOR = ROWPTR + NN + 1;            // [N]
    int* BSUM   = CURSOR + NN;                // [NB]
    int* BOFF   = BSUM + NB;                  // [NB]
    int* CSRS   = BOFF + NB;                  // [E]
    unsigned short* R    = (unsigned short*)(CSRS + NE);
    unsigned short* Abf  = R;                          // [N,192] bf16 features
    unsigned short* W1hT = Abf + (size_t)NN * DD;      // [192,256]
    unsigned short* W1lT = W1hT + W1N;
    unsigned short* W2hT = W1lT + W1N;                 // [192,192]
    unsigned short* W2lT = W2hT + W2N;
    unsigned short* WfhT = W2lT + W2N;                 // [64,192]
    unsigned short* WflT = WfhT + WFN;

    const int edge_grid = (NE + 255) / 256;
    const int gemm_grid = (NN + 63) / 64;
    const int gat_grid  = (NN + 3) / 4;
    const int dots_grid = (NN + 3) / 4;
    const int bns_grid  = (NN + 127) / 128;
    const int wsp_grid  = (W1N + W2N + WFN + 255) / 256;

    // ---- one memset: DEG + four BN stat vectors ----
    hipMemsetAsync(DEG, 0, (size_t)NN * 4 + 4 * DD * 4, stream);

    // ---- CSR build (once) ----
    hist_kernel<<<edge_grid, 256, 0, stream>>>(dst, DEG, NE);
    blocksum_kernel<<<NB, 256, 0, stream>>>(DEG, BSUM);
    scan_bsums<<<1, 256, 0, stream>>>(BSUM, BOFF, ROWPTR);
    expand_kernel<<<NB, 256, 0, stream>>>(DEG, BOFF, ROWPTR, CURSOR);
    scatter_kernel<<<edge_grid, 256, 0, stream>>>(src, dst, CURSOR, CSRS, NE);

    // ---- weight splits ----
    wsplit_all<<<wsp_grid, 256, 0, stream>>>(W1, W2, Wf, W1hT, W1lT, W2hT, W2lT, WfhT, WflT);

    // ================= layer 1 =================
    mfma_gemm<DIN, DD, 0><<<gemm_grid, 256, 0, stream>>>(
        x, nullptr, nullptr, nullptr, nullptr, nullptr, nullptr, nullptr,
        W1hT, W1lT, nullptr, nullptr, Abf, NN);
    attn_dots<<<dots_grid, 256, 0, stream>>>(Abf, as1, ad1, AS4, AD4);
    gat_gather<<<gat_grid, 256, 0, stream>>>(Abf, AS4, AD4, ROWPTR, CSRS, CB1);
    bn_stats<<<bns_grid, 192, 0, stream>>>(CB1, b1, S1a, S2a, NN);
    bn_fin<<<1, DD, 0, stream>>>(S1a, S2a, g1, be1, SC1, SH1);

    // ================= layer 2 (BN1 fused into A-staging) =================
    mfma_gemm<DD, DD, 1><<<gemm_grid, 256, 0, stream>>>(
        CB1, nullptr, b1, SC1, SH1, nullptr, nullptr, nullptr,
        W2hT, W2lT, nullptr, nullptr, Abf, NN);
    attn_dots<<<dots_grid, 256, 0, stream>>>(Abf, as2, ad2, AS4, AD4);
    gat_gather<<<gat_grid, 256, 0, stream>>>(Abf, AS4, AD4, ROWPTR, CSRS, CB2);
    bn_stats<<<bns_grid, 192, 0, stream>>>(CB2, b2, S1b, S2b, NN);
    bn_fin<<<1, DD, 0, stream>>>(S1b, S2b, g2, be2, SC2, SH2);

    // ====== final: out = (bn1(h1) + bn2(h2)) @ Wf + bf (sum fused in staging) ======
    mfma_gemm<DD, DF, 2><<<gemm_grid, 256, 0, stream>>>(
        CB1, CB2, b1, SC1, SH1, b2, SC2, SH2,
        WfhT, WflT, bf, out, nullptr, NN);
}

// Round 10
// 438.407 us; speedup vs baseline: 1.8416x; 1.0467x over previous
//
#include <hip/hip_runtime.h>

#define NN 50000
#define NE 800000
#define DIN 256
#define NH 3
#define HC 64
#define DD 192
#define DF 64
#define NB 196   // (NN + 255) / 256

typedef __attribute__((ext_vector_type(8))) short s8bf;            // 8 bf16 bit-patterns
typedef __attribute__((ext_vector_type(8))) unsigned short u16x8;
typedef __attribute__((ext_vector_type(4))) float f32x4;

// ---- fp32 -> bf16 helpers ----
__device__ __forceinline__ unsigned short f2bf(float f) {
    unsigned u = __float_as_uint(f);
    unsigned r = u + 0x7fffu + ((u >> 16) & 1u);   // round-to-nearest-even
    return (unsigned short)(r >> 16);
}
__device__ __forceinline__ float bf2f(unsigned short h) {
    return __uint_as_float(((unsigned)h) << 16);
}
__device__ __forceinline__ void split2(float f, unsigned short& h, unsigned short& l) {
    h = f2bf(f);
    l = f2bf(f - bf2f(h));
}

// ---- split + transpose all three weights in one dispatch ----
#define W1N (DIN * DD)           // 49152
#define W2N (DD * DD)            // 36864
#define WFN (DD * DF)            // 12288
__global__ __launch_bounds__(256)
void wsplit_all(const float* __restrict__ W1, const float* __restrict__ W2,
                const float* __restrict__ Wf,
                unsigned short* __restrict__ W1hT, unsigned short* __restrict__ W1lT,
                unsigned short* __restrict__ W2hT, unsigned short* __restrict__ W2lT,
                unsigned short* __restrict__ WfhT, unsigned short* __restrict__ WflT) {
    int idx = blockIdx.x * 256 + threadIdx.x;
    const float* W; unsigned short *Wh, *Wl; int K, D, base;
    if (idx < W1N)              { W = W1; Wh = W1hT; Wl = W1lT; K = DIN; D = DD; base = idx; }
    else if (idx < W1N + W2N)   { W = W2; Wh = W2hT; Wl = W2lT; K = DD;  D = DD; base = idx - W1N; }
    else if (idx < W1N + W2N + WFN) { W = Wf; Wh = WfhT; Wl = WflT; K = DD; D = DF; base = idx - W1N - W2N; }
    else return;
    int k = base / D, d = base - k * D;
    unsigned short h, l;
    split2(W[base], h, l);
    Wh[d * K + k] = h;
    Wl[d * K + k] = l;
}

// ---- BN finalize: scale/shift from accumulated stats ----
__global__ void bn_fin(const float* __restrict__ s1, const float* __restrict__ s2,
                       const float* __restrict__ g, const float* __restrict__ beta,
                       float* __restrict__ scale, float* __restrict__ shift) {
    int j = threadIdx.x;
    const float invn = 1.0f / NN;
    float mu = s1[j] * invn;
    float var = s2[j] * invn - mu * mu;
    float sc = g[j] * rsqrtf(var + 1e-5f);
    scale[j] = sc;
    shift[j] = beta[j] - mu * sc;
}

// ---- LDS-staged split-bf16 MFMA GEMM; A built on the fly; dbuf 32-K slices ----
// MODE 0: A = A1 (fp32)                               -> Yb bf16
// MODE 1: A = relu(A1 + bb1)*sc1 + sh1                -> Yb bf16
// MODE 2: A = bn1(A1) + bn2(A2)                       -> Yf fp32 + obias
// DOTS: epilogue computes a_s/a_d per row (att dot products) -> as4o/ad4o
// block = 64 rows x DOUT; 4 waves; LDS slot = row*4+kb == staging tid (conflict-free)
template<int K, int DOUT, int MODE, bool DOTS>
__global__ __launch_bounds__(256)
void mfma_gemm(const float* __restrict__ A1, const float* __restrict__ A2,
               const float* __restrict__ bb1, const float* __restrict__ sc1, const float* __restrict__ sh1,
               const float* __restrict__ bb2, const float* __restrict__ sc2, const float* __restrict__ sh2,
               const unsigned short* __restrict__ BhT, const unsigned short* __restrict__ BlT,
               const float* __restrict__ att_s, const float* __restrict__ att_d,
               float4* __restrict__ as4o, float4* __restrict__ ad4o,
               const float* __restrict__ obias, float* __restrict__ Yf,
               unsigned short* __restrict__ Yb, int n) {
    constexpr int NT = DOUT / 64;            // 16-col tiles per wave (192->3, 64->1)
    __shared__ unsigned short AH[2][256][8]; // 8 KB
    __shared__ unsigned short AL[2][256][8]; // 8 KB
    __shared__ float sdots[DOTS ? 4 : 1][64][6];

    const int tid = threadIdx.x;
    const int wave = tid >> 6, lane = tid & 63;
    const int r = lane & 15, kg = lane >> 4;
    const int row0 = blockIdx.x * 64;
    const int col0 = wave * (DOUT / 4);

    // staging: thread -> (row = tid>>2, kb = tid&3); LDS slot = tid
    const int srow = tid >> 2, skb = tid & 3;
    const int sgrow = min(row0 + srow, n - 1);
    const float* a1p = A1 + (size_t)sgrow * K + skb * 8;
    const float* a2p = (MODE == 2) ? A2 + (size_t)sgrow * K + skb * 8 : nullptr;

    auto stage = [&](int buf, int k0) {
        int j = k0 + skb * 8;
        float v[8];
        *(float4*)&v[0] = *(const float4*)(a1p + k0);
        *(float4*)&v[4] = *(const float4*)(a1p + k0 + 4);
        if constexpr (MODE >= 1) {
#pragma unroll
            for (int q = 0; q < 8; ++q)
                v[q] = fmaxf(v[q] + bb1[j + q], 0.f) * sc1[j + q] + sh1[j + q];
        }
        if constexpr (MODE == 2) {
            float u[8];
            *(float4*)&u[0] = *(const float4*)(a2p + k0);
            *(float4*)&u[4] = *(const float4*)(a2p + k0 + 4);
#pragma unroll
            for (int q = 0; q < 8; ++q)
                v[q] += fmaxf(u[q] + bb2[j + q], 0.f) * sc2[j + q] + sh2[j + q];
        }
        u16x8 hv, lv;
#pragma unroll
        for (int q = 0; q < 8; ++q) {
            unsigned short h, l;
            split2(v[q], h, l);
            hv[q] = h; lv[q] = l;
        }
        *(u16x8*)&AH[buf][tid][0] = hv;
        *(u16x8*)&AL[buf][tid][0] = lv;
    };

    int boff[NT];
#pragma unroll
    for (int t = 0; t < NT; ++t)
        boff[t] = (col0 + t * 16 + r) * K + kg * 8;

    f32x4 acc[4][NT] = {};

    stage(0, 0);
    __syncthreads();

    for (int k0 = 0; k0 < K; k0 += 32) {
        const int buf = (k0 >> 5) & 1;
        if (k0 + 32 < K) stage(buf ^ 1, k0 + 32);

        s8bf bh[NT], bl[NT];
#pragma unroll
        for (int t = 0; t < NT; ++t) {
            bh[t] = *(const s8bf*)(BhT + boff[t] + k0);
            bl[t] = *(const s8bf*)(BlT + boff[t] + k0);
        }
        s8bf ah[4], al[4];
#pragma unroll
        for (int g = 0; g < 4; ++g) {
            int slot = (g * 16 + r) * 4 + kg;
            ah[g] = *(const s8bf*)&AH[buf][slot][0];
            al[g] = *(const s8bf*)&AL[buf][slot][0];
        }
#pragma unroll
        for (int g = 0; g < 4; ++g)
#pragma unroll
            for (int t = 0; t < NT; ++t) {
                acc[g][t] = __builtin_amdgcn_mfma_f32_16x16x32_bf16(ah[g], bh[t], acc[g][t], 0, 0, 0);
                acc[g][t] = __builtin_amdgcn_mfma_f32_16x16x32_bf16(ah[g], bl[t], acc[g][t], 0, 0, 0);
                acc[g][t] = __builtin_amdgcn_mfma_f32_16x16x32_bf16(al[g], bh[t], acc[g][t], 0, 0, 0);
            }
        __syncthreads();
    }

    // ---- C write. layout: col = lane&15 (within tile), row = (lane>>4)*4 + reg ----
#pragma unroll
    for (int t = 0; t < NT; ++t) {
        int col = col0 + t * 16 + r;
        float b = (MODE == 2) ? obias[col] : 0.f;
#pragma unroll
        for (int g = 0; g < 4; ++g) {
#pragma unroll
            for (int rr = 0; rr < 4; ++rr) {
                int row = row0 + g * 16 + kg * 4 + rr;
                if (row < n) {
                    if constexpr (MODE == 2)
                        Yf[(size_t)row * DOUT + col] = acc[g][t][rr] + b;
                    else
                        Yb[(size_t)row * DOUT + col] = f2bf(acc[g][t][rr]);
                }
            }
        }
    }

    // ---- fused attention dots epilogue ----
    if constexpr (DOTS) {
        float asv[NT], adv[NT];
        int headt[NT];
#pragma unroll
        for (int t = 0; t < NT; ++t) {
            int col = col0 + t * 16 + r;
            asv[t] = att_s[col];
            adv[t] = att_d[col];
            headt[t] = (col0 + t * 16) >> 6;   // wave-uniform
        }
#pragma unroll
        for (int g = 0; g < 4; ++g) {
#pragma unroll
            for (int rr = 0; rr < 4; ++rr) {
                float rs0 = 0.f, rs1 = 0.f, rs2 = 0.f;
                float rd0 = 0.f, rd1 = 0.f, rd2 = 0.f;
#pragma unroll
                for (int t = 0; t < NT; ++t) {
                    float v = acc[g][t][rr];
                    float s = v * asv[t], dd = v * adv[t];
                    if (headt[t] == 0)      { rs0 += s; rd0 += dd; }
                    else if (headt[t] == 1) { rs1 += s; rd1 += dd; }
                    else                    { rs2 += s; rd2 += dd; }
                }
#pragma unroll
                for (int m = 1; m < 16; m <<= 1) {
                    rs0 += __shfl_xor(rs0, m); rs1 += __shfl_xor(rs1, m); rs2 += __shfl_xor(rs2, m);
                    rd0 += __shfl_xor(rd0, m); rd1 += __shfl_xor(rd1, m); rd2 += __shfl_xor(rd2, m);
                }
                if (r == 0) {
                    int row = g * 16 + kg * 4 + rr;
                    sdots[wave][row][0] = rs0; sdots[wave][row][1] = rs1; sdots[wave][row][2] = rs2;
                    sdots[wave][row][3] = rd0; sdots[wave][row][4] = rd1; sdots[wave][row][5] = rd2;
                }
            }
        }
        __syncthreads();
        if (tid < 64) {
            int row = row0 + tid;
            if (row < n) {
                float s0 = 0.f, s1 = 0.f, s2 = 0.f, d0 = 0.f, d1 = 0.f, d2 = 0.f;
#pragma unroll
                for (int w = 0; w < 4; ++w) {
                    s0 += sdots[w][tid][0]; s1 += sdots[w][tid][1]; s2 += sdots[w][tid][2];
                    d0 += sdots[w][tid][3]; d1 += sdots[w][tid][4]; d2 += sdots[w][tid][5];
                }
                as4o[row] = make_float4(s0, s1, s2, 0.f);
                ad4o[row] = make_float4(d0, d1, d2, 0.f);
            }
        }
    }
}

// ============ CSR build ============
__global__ void hist_kernel(const int* __restrict__ dst, int* __restrict__ deg, int ne) {
    int e = blockIdx.x * blockDim.x + threadIdx.x;
    if (e < ne) atomicAdd(&deg[dst[e]], 1);
}

__global__ __launch_bounds__(256)
void blocksum_kernel(const int* __restrict__ deg, int* __restrict__ bsum) {
    int i = blockIdx.x * 256 + threadIdx.x;
    int v = (i < NN) ? deg[i] : 0;
#pragma unroll
    for (int off = 32; off; off >>= 1) v += __shfl_down(v, off);
    __shared__ int ws[4];
    if ((threadIdx.x & 63) == 0) ws[threadIdx.x >> 6] = v;
    __syncthreads();
    if (threadIdx.x == 0) bsum[blockIdx.x] = ws[0] + ws[1] + ws[2] + ws[3];
}

__global__ __launch_bounds__(256)
void scan_bsums(const int* __restrict__ bsum, int* __restrict__ boff,
                int* __restrict__ rowptr) {
    __shared__ int s[256];
    int t = threadIdx.x;
    int v = (t < NB) ? bsum[t] : 0;
    s[t] = v;
    __syncthreads();
    for (int off = 1; off < 256; off <<= 1) {
        int u = (t >= off) ? s[t - off] : 0;
        __syncthreads();
        s[t] += u;
        __syncthreads();
    }
    if (t < NB) boff[t] = s[t] - v;
    if (t == 255) rowptr[NN] = s[255];
}

__global__ __launch_bounds__(256)
void expand_kernel(const int* __restrict__ deg, const int* __restrict__ boff,
                   int* __restrict__ rowptr, int* __restrict__ cursor) {
    __shared__ int s[256];
    int t = threadIdx.x;
    int i = blockIdx.x * 256 + t;
    int v = (i < NN) ? deg[i] : 0;
    s[t] = v;
    __syncthreads();
    for (int off = 1; off < 256; off <<= 1) {
        int u = (t >= off) ? s[t - off] : 0;
        __syncthreads();
        s[t] += u;
        __syncthreads();
    }
    if (i < NN) {
        int excl = s[t] - v + boff[blockIdx.x];
        rowptr[i] = excl;
        cursor[i] = excl;
    }
}

__global__ void scatter_kernel(const int* __restrict__ src, const int* __restrict__ dst,
                               int* __restrict__ cursor, int* __restrict__ csr_src, int ne) {
    int e = blockIdx.x * blockDim.x + threadIdx.x;
    if (e >= ne) return;
    int d = dst[e];
    int pos = atomicAdd(&cursor[d], 1);
    csr_src[pos] = src[e];
}

// ============ GAT gather: batched edge prefetch + readlane broadcast ============
__global__ __launch_bounds__(256)
void gat_gather(const unsigned short* __restrict__ xf,
                const float4* __restrict__ as4, const float4* __restrict__ ad4,
                const int* __restrict__ rowptr, const int* __restrict__ csr_src,
                float* __restrict__ outp) {
    int d = blockIdx.x * 4 + (threadIdx.x >> 6);
    if (d >= NN) return;
    const int lane = threadIdx.x & 63;
    const int beg = rowptr[d], end = rowptr[d + 1];
    const float4 adv = ad4[d];

    float a0 = 0.f, a1 = 0.f, a2 = 0.f;
    float den0 = 0.f, den1 = 0.f, den2 = 0.f;

    for (int base = beg; base < end; base += 64) {
        const int nb = min(64, end - base);
        int sl = 0;
        float w0 = 0.f, w1 = 0.f, w2 = 0.f;
        if (lane < nb) {
            sl = csr_src[base + lane];
            float4 av = as4[sl];               // one 16B gather per lane
            float e0 = av.x + adv.x;
            float e1 = av.y + adv.y;
            float e2 = av.z + adv.z;
            e0 = e0 > 0.f ? e0 : 0.2f * e0;
            e1 = e1 > 0.f ? e1 : 0.2f * e1;
            e2 = e2 > 0.f ? e2 : 0.2f * e2;
            w0 = __expf(e0); w1 = __expf(e1); w2 = __expf(e2);
        }
        float r0 = w0, r1 = w1, r2 = w2;
#pragma unroll
        for (int off = 1; off < 64; off <<= 1) {
            r0 += __shfl_xor(r0, off);
            r1 += __shfl_xor(r1, off);
            r2 += __shfl_xor(r2, off);
        }
        den0 += r0; den1 += r1; den2 += r2;

        for (int j = 0; j < nb; ++j) {
            int s = __builtin_amdgcn_readlane(sl, j);
            float u0 = __int_as_float(__builtin_amdgcn_readlane(__float_as_int(w0), j));
            float u1 = __int_as_float(__builtin_amdgcn_readlane(__float_as_int(w1), j));
            float u2 = __int_as_float(__builtin_amdgcn_readlane(__float_as_int(w2), j));
            const unsigned short* xp = xf + (size_t)s * DD;
            a0 = fmaf(bf2f(xp[lane]),       u0, a0);
            a1 = fmaf(bf2f(xp[64 + lane]),  u1, a1);
            a2 = fmaf(bf2f(xp[128 + lane]), u2, a2);
        }
    }
    size_t o = (size_t)d * DD + lane;
    outp[o]       = a0 / (den0 + 1e-16f);
    outp[o + 64]  = a1 / (den1 + 1e-16f);
    outp[o + 128] = a2 / (den2 + 1e-16f);
}

// ---- BN pass 1: per-feature sum / sumsq of relu(h + bias) ----
__global__ __launch_bounds__(192)
void bn_stats(const float* __restrict__ hbuf, const float* __restrict__ bias,
              float* __restrict__ s1, float* __restrict__ s2, int n) {
    int j = threadIdx.x;
    float b = bias[j];
    int r0 = blockIdx.x * 128;
    int r1 = min(r0 + 128, n);
    float a = 0.f, q = 0.f;
    for (int r = r0; r < r1; ++r) {
        float v = hbuf[(size_t)r * DD + j] + b;
        v = fmaxf(v, 0.f);
        a += v; q += v * v;
    }
    atomicAdd(&s1[j], a);
    atomicAdd(&s2[j], q);
}

extern "C" void kernel_launch(void* const* d_in, const int* in_sizes, int n_in,
                              void* d_out, int out_size, void* d_ws, size_t ws_size,
                              hipStream_t stream) {
    const float* x   = (const float*)d_in[0];
    const float* W1  = (const float*)d_in[1];
    const float* as1 = (const float*)d_in[2];
    const float* ad1 = (const float*)d_in[3];
    const float* b1  = (const float*)d_in[4];
    const float* g1  = (const float*)d_in[5];
    const float* be1 = (const float*)d_in[6];
    const float* W2  = (const float*)d_in[7];
    const float* as2 = (const float*)d_in[8];
    const float* ad2 = (const float*)d_in[9];
    const float* b2  = (const float*)d_in[10];
    const float* g2  = (const float*)d_in[11];
    const float* be2 = (const float*)d_in[12];
    const float* Wf  = (const float*)d_in[13];
    const float* bf  = (const float*)d_in[14];
    const int*   ei  = (const int*)d_in[15];
    const int* src = ei;
    const int* dst = ei + NE;
    float* out = (float*)d_out;

    float* ws = (float*)d_ws;
    float* CB1 = ws;                          // [N,192]
    float* CB2 = CB1 + (size_t)NN * DD;       // [N,192]
    float4* AS4 = (float4*)(CB2 + (size_t)NN * DD);   // [N] float4
    float4* AD4 = AS4 + NN;                   // [N] float4
    int* DEG   = (int*)(AD4 + NN);            // [N]  (zeroed together with stats)
    float* S1a = (float*)(DEG + NN);          // [192] x4 stats
    float* S2a = S1a + DD;
    float* S1b = S2a + DD;
    float* S2b = S1b + DD;
    float* SC1 = S2b + DD;                    // [192] x4 scale/shift
    float* SH1 = SC1 + DD;
    float* SC2 = SH1 + DD;
    float* SH2 = SC2 + DD;
    int* ROWPTR = (int*)(SH2 + DD);           // [N+1]
    int* CURSOR = ROWPTR + NN + 1;            // [N]
    int* BSUM   = CURSOR + NN;                // [NB]
    int* BOFF   = BSUM + NB;                  // [NB]
    int* CSRS   = BOFF + NB;                  // [E]
    unsigned short* R    = (unsigned short*)(CSRS + NE);
    unsigned short* Abf  = R;                          // [N,192] bf16 features
    unsigned short* W1hT = Abf + (size_t)NN * DD;      // [192,256]
    unsigned short* W1lT = W1hT + W1N;
    unsigned short* W2hT = W1lT + W1N;                 // [192,192]
    unsigned short* W2lT = W2hT + W2N;
    unsigned short* WfhT = W2lT + W2N;                 // [64,192]
    unsigned short* WflT = WfhT + WFN;

    const int edge_grid = (NE + 255) / 256;
    const int gemm_grid = (NN + 63) / 64;
    const int gat_grid  = (NN + 3) / 4;
    const int bns_grid  = (NN + 127) / 128;
    const int wsp_grid  = (W1N + W2N + WFN + 255) / 256;

    // ---- one memset: DEG + four BN stat vectors ----
    hipMemsetAsync(DEG, 0, (size_t)NN * 4 + 4 * DD * 4, stream);

    // ---- CSR build (once) ----
    hist_kernel<<<edge_grid, 256, 0, stream>>>(dst, DEG, NE);
    blocksum_kernel<<<NB, 256, 0, stream>>>(DEG, BSUM);
    scan_bsums<<<1, 256, 0, stream>>>(BSUM, BOFF, ROWPTR);
    expand_kernel<<<NB, 256, 0, stream>>>(DEG, BOFF, ROWPTR, CURSOR);
    scatter_kernel<<<edge_grid, 256, 0, stream>>>(src, dst, CURSOR, CSRS, NE);

    // ---- weight splits ----
    wsplit_all<<<wsp_grid, 256, 0, stream>>>(W1, W2, Wf, W1hT, W1lT, W2hT, W2lT, WfhT, WflT);

    // ================= layer 1 (dots fused) =================
    mfma_gemm<DIN, DD, 0, true><<<gemm_grid, 256, 0, stream>>>(
        x, nullptr, nullptr, nullptr, nullptr, nullptr, nullptr, nullptr,
        W1hT, W1lT, as1, ad1, AS4, AD4, nullptr, nullptr, Abf, NN);
    gat_gather<<<gat_grid, 256, 0, stream>>>(Abf, AS4, AD4, ROWPTR, CSRS, CB1);
    bn_stats<<<bns_grid, 192, 0, stream>>>(CB1, b1, S1a, S2a, NN);
    bn_fin<<<1, DD, 0, stream>>>(S1a, S2a, g1, be1, SC1, SH1);

    // ================= layer 2 (BN1 + dots fused) =================
    mfma_gemm<DD, DD, 1, true><<<gemm_grid, 256, 0, stream>>>(
        CB1, nullptr, b1, SC1, SH1, nullptr, nullptr, nullptr,
        W2hT, W2lT, as2, ad2, AS4, AD4, nullptr, nullptr, Abf, NN);
    gat_gather<<<gat_grid, 256, 0, stream>>>(Abf, AS4, AD4, ROWPTR, CSRS, CB2);
    bn_stats<<<bns_grid, 192, 0, stream>>>(CB2, b2, S1b, S2b, NN);
    bn_fin<<<1, DD, 0, stream>>>(S1b, S2b, g2, be2, SC2, SH2);

    // ====== final: out = (bn1(h1) + bn2(h2)) @ Wf + bf (sum fused in staging) ======
    mfma_gemm<DD, DF, 2, false><<<gemm_grid, 256, 0, stream>>>(
        CB1, CB2, b1, SC1, SH1, b2, SC2, SH2,
        WfhT, WflT, nullptr, nullptr, nullptr, nullptr, bf, out, nullptr, NN);
}